// Round 1
// baseline (384395.142 us; speedup 1.0000x reference)
//
#include <hip/hip_runtime.h>
#include <hip/hip_bf16.h>

#define HH 512
#define WW 512
#define NB 8
#define TT 16
#define EPSV 1e-5f
#define LAMV 0.1f
#define BS 320   // 5 waves; c2 tile 18x18=324 maps ~1:1 to threads

__device__ __forceinline__ float sigmoidf_(float v) {
    return 1.0f / (1.0f + __expf(-v));
}

// ---------------------------------------------------------------------------
// Guidance pipeline, fully fused: avgpool3 -> dilated conv(1->16)+BN+relu ->
// conv(16->8)+sigmoid. Zero padding everywhere (conv semantics).
// One 16x16 output tile per block.
// ---------------------------------------------------------------------------
__global__ __launch_bounds__(BS) void guidance_kernel(
    const float* __restrict__ x, const float* __restrict__ gw1, const float* __restrict__ gb1,
    const float* __restrict__ bng, const float* __restrict__ bnb, const float* __restrict__ bnm,
    const float* __restrict__ bnv, const float* __restrict__ gw2, const float* __restrict__ gb2,
    float* __restrict__ guid)
{
    __shared__ float s_x[24][25];
    __shared__ float s_xs[22][23];
    __shared__ float s_g[16][18][19];
    const int tid = threadIdx.x;
    const int b  = blockIdx.z;
    const int i0 = blockIdx.y * TT, j0 = blockIdx.x * TT;
    const int o = i0 - 4, p = j0 - 4;
    const float* xb = x + (size_t)b * HH * WW;

    // x tile, ZERO outside image (conv zero-pad semantics)
    for (int e = tid; e < 24 * 24; e += BS) {
        int r = e / 24, c = e % 24;
        int gi = o + r, gj = p + c;
        float v = 0.f;
        if (gi >= 0 && gi < HH && gj >= 0 && gj < WW) v = xb[gi * WW + gj];
        s_x[r][c] = v;
    }
    __syncthreads();

    // xs = avgpool3 at rel [1,23)
    for (int e = tid; e < 22 * 22; e += BS) {
        int r = e / 22 + 1, c = e % 22 + 1;
        int gi = o + r, gj = p + c;
        float v = 0.f;
        if (gi >= 0 && gi < HH && gj >= 0 && gj < WW) {
            float s = 0.f;
            #pragma unroll
            for (int dr = -1; dr <= 1; ++dr)
                #pragma unroll
                for (int dc = -1; dc <= 1; ++dc)
                    s += s_x[r + dr][c + dc];
            v = s * (1.0f / 9.0f);
        }
        s_xs[r - 1][c - 1] = v;
    }
    __syncthreads();

    // g = relu(BN(dilated conv(xs))) at rel [3,21)  (taps at rel +-2,0)
    for (int e = tid; e < 18 * 18; e += BS) {
        int r = e / 18 + 3, c = e % 18 + 3;
        int gi = o + r, gj = p + c;
        bool in = (gi >= 0 && gi < HH && gj >= 0 && gj < WW);
        float acc[16];
        #pragma unroll
        for (int k = 0; k < 16; ++k) acc[k] = gb1[k];
        #pragma unroll
        for (int kh = 0; kh < 3; ++kh)
            #pragma unroll
            for (int kw = 0; kw < 3; ++kw) {
                float v = s_xs[r + 2 * kh - 3][c + 2 * kw - 3];
                #pragma unroll
                for (int k = 0; k < 16; ++k)
                    acc[k] = fmaf(gw1[k * 9 + kh * 3 + kw], v, acc[k]);
            }
        #pragma unroll
        for (int k = 0; k < 16; ++k) {
            float inv = bng[k] * (1.0f / sqrtf(bnv[k] + EPSV));
            float val = acc[k] * inv + (bnb[k] - bnm[k] * inv);
            s_g[k][r - 3][c - 3] = in ? fmaxf(val, 0.f) : 0.f;
        }
    }
    __syncthreads();

    // guidance = sigmoid(conv(g)) at the 16x16 output tile
    if (tid < 256) {
        int r = tid / 16, c = tid % 16;
        int gi = i0 + r, gj = j0 + c;
        float acc[8];
        #pragma unroll
        for (int k = 0; k < 8; ++k) acc[k] = gb2[k];
        for (int ci = 0; ci < 16; ++ci) {
            #pragma unroll
            for (int kh = 0; kh < 3; ++kh)
                #pragma unroll
                for (int kw = 0; kw < 3; ++kw) {
                    float v = s_g[ci][r + kh][c + kw];
                    #pragma unroll
                    for (int k = 0; k < 8; ++k)
                        acc[k] = fmaf(gw2[(k * 16 + ci) * 9 + kh * 3 + kw], v, acc[k]);
                }
        }
        #pragma unroll
        for (int k = 0; k < 8; ++k)
            guid[(((size_t)b * 8 + k) * HH + gi) * WW + gj] = sigmoidf_(acc[k]);
    }
}

// ---------------------------------------------------------------------------
// Z = conv(guidance, cw1[:,4:12]) + cb1  (iteration-invariant part of conv1)
// ---------------------------------------------------------------------------
__global__ __launch_bounds__(256) void z_kernel(
    const float* __restrict__ guid, const float* __restrict__ cw1,
    const float* __restrict__ cb1, float* __restrict__ Z)
{
    size_t idx = (size_t)blockIdx.x * 256 + threadIdx.x;
    int j = (int)(idx % WW);
    int i = (int)((idx / WW) % HH);
    int b = (int)(idx / ((size_t)HH * WW));
    float acc[32];
    #pragma unroll
    for (int k = 0; k < 32; ++k) acc[k] = cb1[k];
    for (int gc = 0; gc < 8; ++gc) {
        const float* gp = guid + ((size_t)(b * 8 + gc)) * HH * WW;
        #pragma unroll
        for (int kh = 0; kh < 3; ++kh) {
            int ii = i + kh - 1;
            if (ii < 0 || ii >= HH) continue;
            #pragma unroll
            for (int kw = 0; kw < 3; ++kw) {
                int jj = j + kw - 1;
                if (jj < 0 || jj >= WW) continue;
                float v = gp[ii * WW + jj];
                #pragma unroll
                for (int k = 0; k < 32; ++k)
                    acc[k] = fmaf(cw1[(k * 12 + 4 + gc) * 9 + kh * 3 + kw], v, acc[k]);
            }
        }
    }
    #pragma unroll
    for (int k = 0; k < 32; ++k)
        Z[(((size_t)b * 32 + k) * HH + i) * WW + j] = acc[k];
}

// ---------------------------------------------------------------------------
// One fused diffusion iteration. 16x16 output tile per block, halo 4 on x.
// grads (edge-clamped) -> conv1(+Z or +guidance part)+relu (8-ch chunks)
// -> conv2+relu (register accumulators) -> conv3+sigmoid -> update.
// Everything off-image is 0 for conv purposes.
// ---------------------------------------------------------------------------
template <bool USE_Z>
__global__ __launch_bounds__(BS) void iter_kernel(
    const float* __restrict__ xin, float* __restrict__ xout,
    const float* __restrict__ zg,   // Z if USE_Z else guidance
    const float* __restrict__ cw1, const float* __restrict__ cb1,
    const float* __restrict__ cw2, const float* __restrict__ cb2,
    const float* __restrict__ cw3, const float* __restrict__ cb3)
{
    __shared__ float s_x[24][25];
    __shared__ float s_grad[4][22][23];
    __shared__ float s_c1[8][20][21];
    __shared__ float s_c2[16][18][19];
    constexpr int GCH = USE_Z ? 1 : 8;
    __shared__ float s_guid[GCH][22][23];

    const int tid = threadIdx.x;
    const int b  = blockIdx.z;
    const int i0 = blockIdx.y * TT, j0 = blockIdx.x * TT;
    const int o = i0 - 4, p = j0 - 4;
    const float* xb = xin + (size_t)b * HH * WW;

    // x tile, CLAMPED (edge-pad semantics for diffusion gradients)
    for (int e = tid; e < 24 * 24; e += BS) {
        int r = e / 24, c = e % 24;
        int gi = min(max(o + r, 0), HH - 1);
        int gj = min(max(p + c, 0), WW - 1);
        s_x[r][c] = xb[gi * WW + gj];
    }
    if constexpr (!USE_Z) {
        // stage guidance tile at rel [1,23), zero outside image
        for (int e = tid; e < 22 * 22; e += BS) {
            int rr = e / 22, cc = e % 22;
            int gi = o + rr + 1, gj = p + cc + 1;
            bool in = (gi >= 0 && gi < HH && gj >= 0 && gj < WW);
            for (int gc = 0; gc < 8; ++gc)
                s_guid[gc][rr][cc] = in ? zg[(((size_t)b * 8 + gc) * HH + gi) * WW + gj] : 0.f;
        }
    }
    __syncthreads();

    // gradients at rel [1,23): value 0 at off-image positions (conv zero-pad)
    for (int e = tid; e < 22 * 22; e += BS) {
        int r = e / 22 + 1, c = e % 22 + 1;
        int gi = o + r, gj = p + c;
        bool in = (gi >= 0 && gi < HH && gj >= 0 && gj < WW);
        float v = s_x[r][c];
        s_grad[0][r - 1][c - 1] = in ? s_x[r - 1][c] - v : 0.f;   // N
        s_grad[1][r - 1][c - 1] = in ? s_x[r + 1][c] - v : 0.f;   // S
        s_grad[2][r - 1][c - 1] = in ? s_x[r][c + 1] - v : 0.f;   // E
        s_grad[3][r - 1][c - 1] = in ? s_x[r][c - 1] - v : 0.f;   // W
    }

    // conv2 accumulators in registers: position tid (always < 324) + 4 extras
    float acc2a[16];
    float acc2b[16];
    #pragma unroll
    for (int co = 0; co < 16; ++co) { acc2a[co] = cb2[co]; acc2b[co] = cb2[co]; }

    for (int ch0 = 0; ch0 < 32; ch0 += 8) {
        __syncthreads();   // (iter0: grads ready) protect s_c1 overwrite
        // c1 chunk [ch0, ch0+8) at rel [2,22): 20x20
        for (int e = tid; e < 20 * 20; e += BS) {
            int r = e / 20 + 2, c = e % 20 + 2;
            int gi = o + r, gj = p + c;
            bool in = (gi >= 0 && gi < HH && gj >= 0 && gj < WW);
            float acc[8];
            if constexpr (USE_Z) {
                #pragma unroll
                for (int k = 0; k < 8; ++k)
                    acc[k] = in ? zg[(((size_t)b * 32 + ch0 + k) * HH + gi) * WW + gj] : 0.f;
            } else {
                #pragma unroll
                for (int k = 0; k < 8; ++k) acc[k] = cb1[ch0 + k];
                for (int gc = 0; gc < 8; ++gc)
                    #pragma unroll
                    for (int t9 = 0; t9 < 9; ++t9) {
                        int dr = t9 / 3 - 1, dc = t9 % 3 - 1;
                        float v = s_guid[gc][r + dr - 1][c + dc - 1];
                        #pragma unroll
                        for (int k = 0; k < 8; ++k)
                            acc[k] = fmaf(cw1[((ch0 + k) * 12 + 4 + gc) * 9 + t9], v, acc[k]);
                    }
            }
            #pragma unroll
            for (int gc = 0; gc < 4; ++gc)
                #pragma unroll
                for (int t9 = 0; t9 < 9; ++t9) {
                    int dr = t9 / 3 - 1, dc = t9 % 3 - 1;
                    float v = s_grad[gc][r + dr - 1][c + dc - 1];
                    #pragma unroll
                    for (int k = 0; k < 8; ++k)
                        acc[k] = fmaf(cw1[((ch0 + k) * 12 + gc) * 9 + t9], v, acc[k]);
                }
            #pragma unroll
            for (int k = 0; k < 8; ++k)
                s_c1[k][r - 2][c - 2] = in ? fmaxf(acc[k], 0.f) : 0.f;
        }
        __syncthreads();
        // accumulate this chunk into c2 registers (c2 at rel [3,21): 18x18)
        {
            int r0 = tid / 18, c0 = tid % 18;
            #pragma unroll
            for (int k = 0; k < 8; ++k)
                #pragma unroll
                for (int t9 = 0; t9 < 9; ++t9) {
                    float va = s_c1[k][r0 + t9 / 3][c0 + t9 % 3];
                    #pragma unroll
                    for (int co = 0; co < 16; ++co)
                        acc2a[co] = fmaf(cw2[(co * 32 + ch0 + k) * 9 + t9], va, acc2a[co]);
                }
            if (tid < 4) {
                int q1 = tid + BS, r1 = q1 / 18, c1 = q1 % 18;
                #pragma unroll
                for (int k = 0; k < 8; ++k)
                    #pragma unroll
                    for (int t9 = 0; t9 < 9; ++t9) {
                        float vb = s_c1[k][r1 + t9 / 3][c1 + t9 % 3];
                        #pragma unroll
                        for (int co = 0; co < 16; ++co)
                            acc2b[co] = fmaf(cw2[(co * 32 + ch0 + k) * 9 + t9], vb, acc2b[co]);
                    }
            }
        }
    }

    // store c2 (relu, zero off-image)
    {
        int r0 = tid / 18, c0 = tid % 18;
        int gi = o + r0 + 3, gj = p + c0 + 3;
        bool in = (gi >= 0 && gi < HH && gj >= 0 && gj < WW);
        #pragma unroll
        for (int co = 0; co < 16; ++co)
            s_c2[co][r0][c0] = in ? fmaxf(acc2a[co], 0.f) : 0.f;
        if (tid < 4) {
            int q1 = tid + BS, r1 = q1 / 18, c1 = q1 % 18;
            gi = o + r1 + 3; gj = p + c1 + 3;
            bool in1 = (gi >= 0 && gi < HH && gj >= 0 && gj < WW);
            #pragma unroll
            for (int co = 0; co < 16; ++co)
                s_c2[co][r1][c1] = in1 ? fmaxf(acc2b[co], 0.f) : 0.f;
        }
    }
    __syncthreads();

    // conv3 + sigmoid + diffusion update on the 16x16 output tile
    if (tid < 256) {
        int r = tid / 16, c = tid % 16;
        float acc[4];
        #pragma unroll
        for (int k = 0; k < 4; ++k) acc[k] = cb3[k];
        for (int ci = 0; ci < 16; ++ci)
            #pragma unroll
            for (int t9 = 0; t9 < 9; ++t9) {
                float v = s_c2[ci][r + t9 / 3][c + t9 % 3];
                #pragma unroll
                for (int k = 0; k < 4; ++k)
                    acc[k] = fmaf(cw3[(k * 16 + ci) * 9 + t9], v, acc[k]);
            }
        float cN = sigmoidf_(acc[0]), cS = sigmoidf_(acc[1]);
        float cE = sigmoidf_(acc[2]), cWd = sigmoidf_(acc[3]);
        int rr = r + 4, cc = c + 4;
        float v  = s_x[rr][cc];
        float gN = s_x[rr - 1][cc] - v;
        float gS = s_x[rr + 1][cc] - v;
        float gE = s_x[rr][cc + 1] - v;
        float gW = s_x[rr][cc - 1] - v;
        xout[((size_t)b * HH + (i0 + r)) * WW + (j0 + c)] =
            v + LAMV * (cN * gN + cS * gS + cE * gE + cWd * gW);
    }
}

extern "C" void kernel_launch(void* const* d_in, const int* in_sizes, int n_in,
                              void* d_out, int out_size, void* d_ws, size_t ws_size,
                              hipStream_t stream) {
    (void)in_sizes; (void)n_in; (void)out_size;
    const float* x   = (const float*)d_in[0];
    const float* gw1 = (const float*)d_in[1];
    const float* gb1 = (const float*)d_in[2];
    const float* bng = (const float*)d_in[3];
    const float* bnb = (const float*)d_in[4];
    const float* bnm = (const float*)d_in[5];
    const float* bnv = (const float*)d_in[6];
    const float* gw2 = (const float*)d_in[7];
    const float* gb2 = (const float*)d_in[8];
    const float* cw1 = (const float*)d_in[9];
    const float* cb1 = (const float*)d_in[10];
    const float* cw2 = (const float*)d_in[11];
    const float* cb2 = (const float*)d_in[12];
    const float* cw3 = (const float*)d_in[13];
    const float* cb3 = (const float*)d_in[14];
    float* out = (float*)d_out;

    float* w = (float*)d_ws;
    const size_t ZE = 8ull * 32 * HH * WW;   // 67,108,864 floats (256 MB)
    const size_t GE = 8ull * 8 * HH * WW;    // 16,777,216 floats (64 MB)
    const size_t XE = 8ull * HH * WW;        //  2,097,152 floats (8 MB)
    const bool use_z = ws_size >= (ZE + GE + 2 * XE) * sizeof(float);

    float *Z, *guid, *bufA, *bufB;
    if (use_z) { Z = w; guid = w + ZE; bufA = guid + GE; bufB = bufA + XE; }
    else       { Z = nullptr; guid = w; bufA = guid + GE; bufB = bufA + XE; }

    dim3 grid(WW / TT, HH / TT, NB);
    guidance_kernel<<<grid, BS, 0, stream>>>(x, gw1, gb1, bng, bnb, bnm, bnv, gw2, gb2, guid);
    if (use_z)
        z_kernel<<<(NB * HH * WW) / 256, 256, 0, stream>>>(guid, cw1, cb1, Z);

    const float* cur = x;
    for (int it = 0; it < 10; ++it) {
        float* dst = (it == 9) ? out : ((it & 1) ? bufB : bufA);
        if (use_z)
            iter_kernel<true><<<grid, BS, 0, stream>>>(cur, dst, Z, cw1, cb1, cw2, cb2, cw3, cb3);
        else
            iter_kernel<false><<<grid, BS, 0, stream>>>(cur, dst, guid, cw1, cb1, cw2, cb2, cw3, cb3);
        cur = dst;
    }
}

// Round 2
// 23188.907 us; speedup vs baseline: 16.5767x; 16.5767x over previous
//
#include <hip/hip_runtime.h>
#include <hip/hip_bf16.h>

#define HH 512
#define WW 512
#define NB 8
#define TT 16
#define BS 384
#define EPSV 1e-5f
#define LAMV 0.1f

__device__ __forceinline__ float sigmoidf_(float v) {
    return 1.0f / (1.0f + __expf(-v));
}

// union region: s_grad [4][22][23] @0 (8096B) + s_c1 [8][20][21] @8096 (13440B)
// aliased later by s_c2 [16][18][19] @0 (21888B)
#define S_GRAD(g,a,b2) (((float*)s_u)[((g)*22+(a))*23+(b2)])
#define S_C1(k,a,b2)   (((float*)(s_u+8096))[((k)*20+(a))*21+(b2)])
#define S_C2(k,a,b2)   (((float*)s_u)[((k)*18+(a))*19+(b2)])

// ---------------------------------------------------------------------------
// Guidance: avgpool3 -> dilated conv(1->16)+BN+relu -> conv(16->8)+sigmoid.
// All weights staged in LDS. 16x16 output tile per block.
// ---------------------------------------------------------------------------
__global__ __launch_bounds__(BS) void guidance_kernel(
    const float* __restrict__ x, const float* __restrict__ gw1, const float* __restrict__ gb1,
    const float* __restrict__ bng, const float* __restrict__ bnb, const float* __restrict__ bnm,
    const float* __restrict__ bnv, const float* __restrict__ gw2, const float* __restrict__ gb2,
    float* __restrict__ guid)
{
    __shared__ __align__(16) float s_wg1[9][16];
    __shared__ __align__(16) float s_wg2[16][9][8];
    __shared__ float s_inv[16], s_off[16], s_b1[16], s_b2[8];
    __shared__ float s_x[24][25];
    __shared__ float s_xs[22][23];
    __shared__ float s_g[16][18][19];

    const int tid = threadIdx.x;
    const int b  = blockIdx.z;
    const int i0 = blockIdx.y * TT, j0 = blockIdx.x * TT;
    const int o = i0 - 4, p = j0 - 4;
    const float* xb = x + (size_t)b * HH * WW;

    for (int e = tid; e < 144; e += BS) {
        int co = e % 16, t = e / 16;
        s_wg1[t][co] = gw1[co * 9 + t];
    }
    for (int e = tid; e < 1152; e += BS) {
        int co = e % 8, t = (e / 8) % 9, ci = e / 72;
        s_wg2[ci][t][co] = gw2[(co * 16 + ci) * 9 + t];
    }
    if (tid < 16) {
        float iv = bng[tid] * rsqrtf(bnv[tid] + EPSV);
        s_inv[tid] = iv;
        s_off[tid] = bnb[tid] - bnm[tid] * iv;
        s_b1[tid]  = gb1[tid];
    }
    if (tid < 8) s_b2[tid] = gb2[tid];

    // x tile, ZERO outside image (conv zero-pad semantics)
    for (int e = tid; e < 576; e += BS) {
        int r = e / 24, c = e % 24;
        int gi = o + r, gj = p + c;
        float v = 0.f;
        if (gi >= 0 && gi < HH && gj >= 0 && gj < WW) v = xb[gi * WW + gj];
        s_x[r][c] = v;
    }
    __syncthreads();

    // xs = avgpool3 at rel [1,23)
    for (int e = tid; e < 484; e += BS) {
        int a = e / 22, bb = e % 22;
        int gi = o + a + 1, gj = p + bb + 1;
        float v = 0.f;
        if (gi >= 0 && gi < HH && gj >= 0 && gj < WW) {
            float s = 0.f;
            #pragma unroll
            for (int dr = 0; dr < 3; ++dr)
                #pragma unroll
                for (int dc = 0; dc < 3; ++dc)
                    s += s_x[a + dr][bb + dc];
            v = s * (1.0f / 9.0f);
        }
        s_xs[a][bb] = v;
    }
    __syncthreads();

    // g = relu(BN(dilated conv(xs))) at rel [3,21)
    for (int e = tid; e < 324; e += BS) {
        int a = e / 18, bb = e % 18;
        int gi = o + a + 3, gj = p + bb + 3;
        bool in = (gi >= 0 && gi < HH && gj >= 0 && gj < WW);
        float acc[16];
        #pragma unroll
        for (int k = 0; k < 16; ++k) acc[k] = s_b1[k];
        #pragma unroll
        for (int kh = 0; kh < 3; ++kh)
            #pragma unroll
            for (int kw = 0; kw < 3; ++kw) {
                float av = s_xs[a + 2 * kh][bb + 2 * kw];
                #pragma unroll
                for (int q4 = 0; q4 < 4; ++q4) {
                    const float4 w = *(const float4*)&s_wg1[kh * 3 + kw][q4 * 4];
                    acc[q4*4+0] = fmaf(w.x, av, acc[q4*4+0]);
                    acc[q4*4+1] = fmaf(w.y, av, acc[q4*4+1]);
                    acc[q4*4+2] = fmaf(w.z, av, acc[q4*4+2]);
                    acc[q4*4+3] = fmaf(w.w, av, acc[q4*4+3]);
                }
            }
        #pragma unroll
        for (int k = 0; k < 16; ++k) {
            float val = acc[k] * s_inv[k] + s_off[k];
            s_g[k][a][bb] = in ? fmaxf(val, 0.f) : 0.f;
        }
    }
    __syncthreads();

    // guidance = sigmoid(conv(g)) on the 16x16 tile
    if (tid < 256) {
        int a = tid / 16, bb = tid % 16;
        int gi = i0 + a, gj = j0 + bb;
        float acc[8];
        #pragma unroll
        for (int k = 0; k < 8; ++k) acc[k] = s_b2[k];
        for (int ci = 0; ci < 16; ++ci)
            #pragma unroll
            for (int t9 = 0; t9 < 9; ++t9) {
                float av = s_g[ci][a + t9 / 3][bb + t9 % 3];
                #pragma unroll
                for (int q4 = 0; q4 < 2; ++q4) {
                    const float4 w = *(const float4*)&s_wg2[ci][t9][q4 * 4];
                    acc[q4*4+0] = fmaf(w.x, av, acc[q4*4+0]);
                    acc[q4*4+1] = fmaf(w.y, av, acc[q4*4+1]);
                    acc[q4*4+2] = fmaf(w.z, av, acc[q4*4+2]);
                    acc[q4*4+3] = fmaf(w.w, av, acc[q4*4+3]);
                }
            }
        #pragma unroll
        for (int k = 0; k < 8; ++k)
            guid[(((size_t)b * 8 + k) * HH + gi) * WW + gj] = sigmoidf_(acc[k]);
    }
}

// ---------------------------------------------------------------------------
// Z = cb1 + conv(guidance, cw1[:,4:12])  (iteration-invariant part of conv1)
// Pixel-major layout [b][i][j][32]; fp32 (zmode=2) or bf16 (zmode=1).
// ---------------------------------------------------------------------------
__global__ __launch_bounds__(256) void z_kernel(
    const float* __restrict__ guid, const float* __restrict__ cw1,
    const float* __restrict__ cb1, float* __restrict__ Zf,
    unsigned short* __restrict__ Zh, const int zmode)
{
    __shared__ __align__(16) float s_wg[8][9][32];
    __shared__ float s_gub[8][18][20];
    __shared__ float s_b1[32];

    const int tid = threadIdx.x;
    const int b  = blockIdx.z;
    const int i0 = blockIdx.y * TT, j0 = blockIdx.x * TT;

    for (int e = tid; e < 2304; e += 256) {
        int co = e % 32, t = (e / 32) % 9, g = e / 288;
        s_wg[g][t][co] = cw1[(co * 12 + 4 + g) * 9 + t];
    }
    if (tid < 32) s_b1[tid] = cb1[tid];
    for (int e = tid; e < 2592; e += 256) {
        int g = e / 324, q = e % 324, a = q / 18, bb = q % 18;
        int gi = i0 + a - 1, gj = j0 + bb - 1;
        bool in = (gi >= 0 && gi < HH && gj >= 0 && gj < WW);
        s_gub[g][a][bb] = in ? guid[(((size_t)b * 8 + g) * HH + gi) * WW + gj] : 0.f;
    }
    __syncthreads();

    const int a = tid / 16, bb = tid % 16;
    const int gi = i0 + a, gj = j0 + bb;
    float acc[32];
    #pragma unroll
    for (int k = 0; k < 32; ++k) acc[k] = s_b1[k];

    for (int g = 0; g < 8; ++g)
        #pragma unroll
        for (int t9 = 0; t9 < 9; ++t9) {
            float av = s_gub[g][a + t9 / 3][bb + t9 % 3];
            #pragma unroll
            for (int q4 = 0; q4 < 8; ++q4) {
                const float4 w = *(const float4*)&s_wg[g][t9][q4 * 4];
                acc[q4*4+0] = fmaf(w.x, av, acc[q4*4+0]);
                acc[q4*4+1] = fmaf(w.y, av, acc[q4*4+1]);
                acc[q4*4+2] = fmaf(w.z, av, acc[q4*4+2]);
                acc[q4*4+3] = fmaf(w.w, av, acc[q4*4+3]);
            }
        }

    if (zmode == 2) {
        float* zp = Zf + (((size_t)b * HH + gi) * WW + gj) * 32;
        #pragma unroll
        for (int q4 = 0; q4 < 8; ++q4) {
            float4 v = { acc[q4*4+0], acc[q4*4+1], acc[q4*4+2], acc[q4*4+3] };
            *(float4*)(zp + q4 * 4) = v;
        }
    } else {
        unsigned short* zp = Zh + (((size_t)b * HH + gi) * WW + gj) * 32;
        #pragma unroll
        for (int q = 0; q < 32; q += 2) {
            __hip_bfloat16 h0 = __float2bfloat16(acc[q]);
            __hip_bfloat16 h1 = __float2bfloat16(acc[q + 1]);
            unsigned short u0, u1;
            __builtin_memcpy(&u0, &h0, 2);
            __builtin_memcpy(&u1, &h1, 2);
            *(unsigned int*)(zp + q) = (unsigned int)u0 | ((unsigned int)u1 << 16);
        }
    }
}

// ---------------------------------------------------------------------------
// One fused diffusion iteration. ZM: 0 = recompute guidance part (no Z),
// 1 = Z bf16, 2 = Z f32. All weights in LDS; conv2 mapped 4pos x 4co/thread.
// ---------------------------------------------------------------------------
template <int ZM>
__global__ __launch_bounds__(BS) void iter_kernel(
    const float* __restrict__ xin, float* __restrict__ xout,
    const float* __restrict__ Zf, const unsigned short* __restrict__ Zh,
    const float* __restrict__ guid,
    const float* __restrict__ cw1, const float* __restrict__ cb1,
    const float* __restrict__ cw2, const float* __restrict__ cb2,
    const float* __restrict__ cw3, const float* __restrict__ cb3)
{
    constexpr int GC = (ZM == 0) ? 12 : 4;
    __shared__ __align__(16) float s_w1[GC][9][32];
    __shared__ __align__(16) float s_w2[32][9][16];
    __shared__ __align__(16) float s_w3[16][9][4];
    __shared__ float s_bias[52];          // [0..31] cb1 (ZM==0), [32..47] cb2, [48..51] cb3
    __shared__ float s_x[24][25];
    __shared__ __align__(16) char s_u[21888];
    __shared__ float s_gu[(ZM == 0) ? 8 : 1][22][24];

    const int tid = threadIdx.x;
    const int b  = blockIdx.z;
    const int i0 = blockIdx.y * TT, j0 = blockIdx.x * TT;
    const int o = i0 - 4, p = j0 - 4;
    const float* xb = xin + (size_t)b * HH * WW;

    // ---- stage weights ----
    for (int e = tid; e < GC * 288; e += BS) {
        int co = e % 32, t = (e / 32) % 9, gc = e / 288;
        s_w1[gc][t][co] = cw1[(co * 12 + gc) * 9 + t];
    }
    for (int e = tid; e < 4608; e += BS) {
        int co = e % 16, t = (e / 16) % 9, k = e / 144;
        s_w2[k][t][co] = cw2[(co * 32 + k) * 9 + t];
    }
    for (int e = tid; e < 576; e += BS) {
        int co = e & 3, t = (e >> 2) % 9, ci = e / 36;
        s_w3[ci][t][co] = cw3[(co * 16 + ci) * 9 + t];
    }
    if (ZM == 0 && tid < 32) s_bias[tid] = cb1[tid];
    if (tid < 16) s_bias[32 + tid] = cb2[tid];
    if (tid < 4)  s_bias[48 + tid] = cb3[tid];

    // ---- stage x (CLAMPED: edge-pad for diffusion gradients) ----
    for (int e = tid; e < 576; e += BS) {
        int r = e / 24, c = e % 24;
        int gi = min(max(o + r, 0), HH - 1);
        int gj = min(max(p + c, 0), WW - 1);
        s_x[r][c] = xb[gi * WW + gj];
    }
    if constexpr (ZM == 0) {
        for (int e = tid; e < 484; e += BS) {
            int a = e / 22, bb = e % 22;
            int gi = o + a + 1, gj = p + bb + 1;
            bool in = (gi >= 0 && gi < HH && gj >= 0 && gj < WW);
            for (int g = 0; g < 8; ++g)
                s_gu[g][a][bb] = in ? guid[(((size_t)b * 8 + g) * HH + gi) * WW + gj] : 0.f;
        }
    }
    __syncthreads();   // B1

    // ---- gradients at rel [1,23), 0 off-image (conv zero-pad) ----
    for (int e = tid; e < 484; e += BS) {
        int a = e / 22, bb = e % 22;
        int gi = o + a + 1, gj = p + bb + 1;
        bool in = (gi >= 0 && gi < HH && gj >= 0 && gj < WW);
        float v = s_x[a + 1][bb + 1];
        S_GRAD(0, a, bb) = in ? s_x[a][bb + 1] - v : 0.f;      // N
        S_GRAD(1, a, bb) = in ? s_x[a + 2][bb + 1] - v : 0.f;  // S
        S_GRAD(2, a, bb) = in ? s_x[a + 1][bb + 2] - v : 0.f;  // E
        S_GRAD(3, a, bb) = in ? s_x[a + 1][bb] - v : 0.f;      // W
    }

    // ---- conv2 accumulators: thread = 4 positions x 4 out-channels ----
    const int cg = tid & 3;
    int pr[4], pc[4];
    if (tid < 324) {
        #pragma unroll
        for (int i = 0; i < 4; ++i) {
            int pi = (tid >> 2) * 4 + i;
            pr[i] = pi / 18; pc[i] = pi % 18;
        }
    }
    float acc2[16];
    #pragma unroll
    for (int i = 0; i < 4; ++i)
        #pragma unroll
        for (int j = 0; j < 4; ++j) acc2[i * 4 + j] = s_bias[32 + cg * 4 + j];

    #pragma unroll 1
    for (int ch0 = 0; ch0 < 32; ch0 += 8) {
        __syncthreads();   // B2: grads ready (it0) / prev c2-accum done (it>0)

        // c1 chunk at rel [2,22): 20x20, 8 out-channels per thread-position
        for (int e = tid; e < 400; e += BS) {
            const int a = e / 20, bb = e % 20;
            const int gi = o + a + 2, gj = p + bb + 2;
            const bool in = (gi >= 0 && gi < HH && gj >= 0 && gj < WW);
            float acc[8];
            if constexpr (ZM == 2) {
                if (in) {
                    const float* zp = Zf + (((size_t)b * HH + gi) * WW + gj) * 32 + ch0;
                    const float4 z0 = *(const float4*)zp;
                    const float4 z1 = *(const float4*)(zp + 4);
                    acc[0]=z0.x; acc[1]=z0.y; acc[2]=z0.z; acc[3]=z0.w;
                    acc[4]=z1.x; acc[5]=z1.y; acc[6]=z1.z; acc[7]=z1.w;
                } else {
                    #pragma unroll
                    for (int k = 0; k < 8; ++k) acc[k] = 0.f;
                }
            } else if constexpr (ZM == 1) {
                if (in) {
                    const uint4 zr = *(const uint4*)(Zh + (((size_t)b * HH + gi) * WW + gj) * 32 + ch0);
                    acc[0]=__uint_as_float(zr.x << 16); acc[1]=__uint_as_float(zr.x & 0xffff0000u);
                    acc[2]=__uint_as_float(zr.y << 16); acc[3]=__uint_as_float(zr.y & 0xffff0000u);
                    acc[4]=__uint_as_float(zr.z << 16); acc[5]=__uint_as_float(zr.z & 0xffff0000u);
                    acc[6]=__uint_as_float(zr.w << 16); acc[7]=__uint_as_float(zr.w & 0xffff0000u);
                } else {
                    #pragma unroll
                    for (int k = 0; k < 8; ++k) acc[k] = 0.f;
                }
            } else {
                #pragma unroll
                for (int k = 0; k < 8; ++k) acc[k] = s_bias[ch0 + k];
            }
            #pragma unroll
            for (int gc = 0; gc < GC; ++gc)
                #pragma unroll
                for (int t9 = 0; t9 < 9; ++t9) {
                    const int dr = t9 / 3, dc = t9 % 3;
                    float av;
                    if (gc < 4) av = S_GRAD(gc, a + dr, bb + dc);
                    else        av = s_gu[gc - 4][a + dr][bb + dc];
                    const float4 w0 = *(const float4*)&s_w1[gc][t9][ch0];
                    const float4 w1 = *(const float4*)&s_w1[gc][t9][ch0 + 4];
                    acc[0]=fmaf(w0.x,av,acc[0]); acc[1]=fmaf(w0.y,av,acc[1]);
                    acc[2]=fmaf(w0.z,av,acc[2]); acc[3]=fmaf(w0.w,av,acc[3]);
                    acc[4]=fmaf(w1.x,av,acc[4]); acc[5]=fmaf(w1.y,av,acc[5]);
                    acc[6]=fmaf(w1.z,av,acc[6]); acc[7]=fmaf(w1.w,av,acc[7]);
                }
            #pragma unroll
            for (int k = 0; k < 8; ++k)
                S_C1(k, a, bb) = in ? fmaxf(acc[k], 0.f) : 0.f;
        }
        __syncthreads();   // B3: s_c1 ready

        if (tid < 324) {
            #pragma unroll
            for (int kk = 0; kk < 8; ++kk)
                #pragma unroll
                for (int t9 = 0; t9 < 9; ++t9) {
                    const int dr = t9 / 3, dc = t9 % 3;
                    const float4 w = *(const float4*)&s_w2[ch0 + kk][t9][cg * 4];
                    #pragma unroll
                    for (int i = 0; i < 4; ++i) {
                        const float av = S_C1(kk, pr[i] + dr, pc[i] + dc);
                        acc2[i*4+0] = fmaf(w.x, av, acc2[i*4+0]);
                        acc2[i*4+1] = fmaf(w.y, av, acc2[i*4+1]);
                        acc2[i*4+2] = fmaf(w.z, av, acc2[i*4+2]);
                        acc2[i*4+3] = fmaf(w.w, av, acc2[i*4+3]);
                    }
                }
        }
    }

    __syncthreads();   // B4: last c2-accum done reading s_c1
    if (tid < 324) {
        #pragma unroll
        for (int i = 0; i < 4; ++i) {
            const int gi = o + pr[i] + 3, gj = p + pc[i] + 3;
            const bool in = (gi >= 0 && gi < HH && gj >= 0 && gj < WW);
            #pragma unroll
            for (int j = 0; j < 4; ++j)
                S_C2(cg * 4 + j, pr[i], pc[i]) = in ? fmaxf(acc2[i * 4 + j], 0.f) : 0.f;
        }
    }
    __syncthreads();   // B5

    // ---- conv3 + sigmoid + diffusion update ----
    if (tid < 256) {
        const int a = tid / 16, bb = tid % 16;
        float acc3[4];
        #pragma unroll
        for (int k = 0; k < 4; ++k) acc3[k] = s_bias[48 + k];
        for (int ci = 0; ci < 16; ++ci)
            #pragma unroll
            for (int t9 = 0; t9 < 9; ++t9) {
                const float av = S_C2(ci, a + t9 / 3, bb + t9 % 3);
                const float4 w = *(const float4*)&s_w3[ci][t9][0];
                acc3[0] = fmaf(w.x, av, acc3[0]);
                acc3[1] = fmaf(w.y, av, acc3[1]);
                acc3[2] = fmaf(w.z, av, acc3[2]);
                acc3[3] = fmaf(w.w, av, acc3[3]);
            }
        const float cN = sigmoidf_(acc3[0]), cS = sigmoidf_(acc3[1]);
        const float cE = sigmoidf_(acc3[2]), cWd = sigmoidf_(acc3[3]);
        const float v  = s_x[a + 4][bb + 4];
        const float gN = s_x[a + 3][bb + 4] - v;
        const float gS = s_x[a + 5][bb + 4] - v;
        const float gE = s_x[a + 4][bb + 5] - v;
        const float gW = s_x[a + 4][bb + 3] - v;
        xout[((size_t)b * HH + (i0 + a)) * WW + (j0 + bb)] =
            v + LAMV * (cN * gN + cS * gS + cE * gE + cWd * gW);
    }
}

extern "C" void kernel_launch(void* const* d_in, const int* in_sizes, int n_in,
                              void* d_out, int out_size, void* d_ws, size_t ws_size,
                              hipStream_t stream) {
    (void)in_sizes; (void)n_in; (void)out_size;
    const float* x   = (const float*)d_in[0];
    const float* gw1 = (const float*)d_in[1];
    const float* gb1 = (const float*)d_in[2];
    const float* bng = (const float*)d_in[3];
    const float* bnb = (const float*)d_in[4];
    const float* bnm = (const float*)d_in[5];
    const float* bnv = (const float*)d_in[6];
    const float* gw2 = (const float*)d_in[7];
    const float* gb2 = (const float*)d_in[8];
    const float* cw1 = (const float*)d_in[9];
    const float* cb1 = (const float*)d_in[10];
    const float* cw2 = (const float*)d_in[11];
    const float* cb2 = (const float*)d_in[12];
    const float* cw3 = (const float*)d_in[13];
    const float* cb3 = (const float*)d_in[14];
    float* out = (float*)d_out;

    char* base = (char*)d_ws;
    const size_t PX   = (size_t)NB * HH * WW;
    const size_t Z32B = PX * 32 * 4;   // 256 MiB
    const size_t Z16B = PX * 32 * 2;   // 128 MiB
    const size_t GUB  = PX * 8 * 4;    //  64 MiB
    const size_t XB   = PX * 4;        //   8 MiB

    int zmode;
    if      (ws_size >= Z32B + GUB + XB) zmode = 2;
    else if (ws_size >= Z16B + GUB + XB) zmode = 1;
    else                                 zmode = 0;

    float* Zf = nullptr; unsigned short* Zh = nullptr;
    float *guidp, *bufA;
    if (zmode == 2) { Zf = (float*)base;          guidp = (float*)(base + Z32B); bufA = (float*)(base + Z32B + GUB); }
    else if (zmode == 1) { Zh = (unsigned short*)base; guidp = (float*)(base + Z16B); bufA = (float*)(base + Z16B + GUB); }
    else { guidp = (float*)base; bufA = (float*)(base + GUB); }

    dim3 grid(WW / TT, HH / TT, NB);
    guidance_kernel<<<grid, BS, 0, stream>>>(x, gw1, gb1, bng, bnb, bnm, bnv, gw2, gb2, guidp);
    if (zmode)
        z_kernel<<<grid, 256, 0, stream>>>(guidp, cw1, cb1, Zf, Zh, zmode);

    const float* cur = x;
    for (int it = 0; it < 10; ++it) {
        float* dst = (it & 1) ? out : bufA;   // it9 (odd) lands in d_out
        if (zmode == 2)
            iter_kernel<2><<<grid, BS, 0, stream>>>(cur, dst, Zf, Zh, guidp, cw1, cb1, cw2, cb2, cw3, cb3);
        else if (zmode == 1)
            iter_kernel<1><<<grid, BS, 0, stream>>>(cur, dst, Zf, Zh, guidp, cw1, cb1, cw2, cb2, cw3, cb3);
        else
            iter_kernel<0><<<grid, BS, 0, stream>>>(cur, dst, Zf, Zh, guidp, cw1, cb1, cw2, cb2, cw3, cb3);
        cur = dst;
    }
}

// Round 4
// 4108.704 us; speedup vs baseline: 93.5563x; 5.6438x over previous
//
#include <hip/hip_runtime.h>
#include <hip/hip_bf16.h>

#define HH 512
#define WW 512
#define NB 8
#define TT 16
#define BSG 384
#define BSI 256
#define EPSV 1e-5f
#define LAMV 0.1f

typedef __attribute__((ext_vector_type(4))) float f32x4;
typedef __attribute__((ext_vector_type(4))) short s16x4;
typedef __attribute__((ext_vector_type(8))) short s16x8;

#define MFMA16 __builtin_amdgcn_mfma_f32_16x16x32_bf16

__device__ __forceinline__ float sigmoidf_(float v) { return 1.0f / (1.0f + __expf(-v)); }

__device__ __forceinline__ short f2bf(float f) {
    __hip_bfloat16 h = __float2bfloat16(f);
    short s; __builtin_memcpy(&s, &h, 2); return s;
}
__device__ __forceinline__ unsigned pack2bf(float a, float b) {
    __hip_bfloat16 ha = __float2bfloat16(a), hb = __float2bfloat16(b);
    unsigned short ua, ub;
    __builtin_memcpy(&ua, &ha, 2); __builtin_memcpy(&ub, &hb, 2);
    return (unsigned)ua | ((unsigned)ub << 16);
}
__device__ __forceinline__ float bfbits2f(unsigned u16) {
    unsigned x = u16 << 16; float f; __builtin_memcpy(&f, &x, 4); return f;
}

// ---------------------------------------------------------------------------
// Guidance: avgpool3 -> dilated conv(1->16)+BN+relu -> conv(16->8)+sigmoid.
// (runs once; f32, weights in LDS — benchmarked cheap in round 2)
// ---------------------------------------------------------------------------
__global__ __launch_bounds__(BSG) void guidance_kernel(
    const float* __restrict__ x, const float* __restrict__ gw1, const float* __restrict__ gb1,
    const float* __restrict__ bng, const float* __restrict__ bnb, const float* __restrict__ bnm,
    const float* __restrict__ bnv, const float* __restrict__ gw2, const float* __restrict__ gb2,
    float* __restrict__ guid)
{
    __shared__ __align__(16) float s_wg1[9][16];
    __shared__ __align__(16) float s_wg2[16][9][8];
    __shared__ float s_inv[16], s_off[16], s_b1[16], s_b2[8];
    __shared__ float s_x[24][25];
    __shared__ float s_xs[22][23];
    __shared__ float s_g[16][18][19];

    const int tid = threadIdx.x;
    const int b  = blockIdx.z;
    const int i0 = blockIdx.y * TT, j0 = blockIdx.x * TT;
    const int o = i0 - 4, p = j0 - 4;
    const float* xb = x + (size_t)b * HH * WW;

    for (int e = tid; e < 144; e += BSG) { int co = e % 16, t = e / 16; s_wg1[t][co] = gw1[co * 9 + t]; }
    for (int e = tid; e < 1152; e += BSG) {
        int co = e % 8, t = (e / 8) % 9, ci = e / 72;
        s_wg2[ci][t][co] = gw2[(co * 16 + ci) * 9 + t];
    }
    if (tid < 16) {
        float iv = bng[tid] * rsqrtf(bnv[tid] + EPSV);
        s_inv[tid] = iv; s_off[tid] = bnb[tid] - bnm[tid] * iv; s_b1[tid] = gb1[tid];
    }
    if (tid < 8) s_b2[tid] = gb2[tid];

    for (int e = tid; e < 576; e += BSG) {
        int r = e / 24, c = e % 24;
        int gi = o + r, gj = p + c;
        float v = 0.f;
        if (gi >= 0 && gi < HH && gj >= 0 && gj < WW) v = xb[gi * WW + gj];
        s_x[r][c] = v;
    }
    __syncthreads();

    for (int e = tid; e < 484; e += BSG) {
        int a = e / 22, bb = e % 22;
        int gi = o + a + 1, gj = p + bb + 1;
        float v = 0.f;
        if (gi >= 0 && gi < HH && gj >= 0 && gj < WW) {
            float s = 0.f;
            #pragma unroll
            for (int dr = 0; dr < 3; ++dr)
                #pragma unroll
                for (int dc = 0; dc < 3; ++dc) s += s_x[a + dr][bb + dc];
            v = s * (1.0f / 9.0f);
        }
        s_xs[a][bb] = v;
    }
    __syncthreads();

    for (int e = tid; e < 324; e += BSG) {
        int a = e / 18, bb = e % 18;
        int gi = o + a + 3, gj = p + bb + 3;
        bool in = (gi >= 0 && gi < HH && gj >= 0 && gj < WW);
        float acc[16];
        #pragma unroll
        for (int k = 0; k < 16; ++k) acc[k] = s_b1[k];
        #pragma unroll
        for (int kh = 0; kh < 3; ++kh)
            #pragma unroll
            for (int kw = 0; kw < 3; ++kw) {
                float av = s_xs[a + 2 * kh][bb + 2 * kw];
                #pragma unroll
                for (int q4 = 0; q4 < 4; ++q4) {
                    const float4 w = *(const float4*)&s_wg1[kh * 3 + kw][q4 * 4];
                    acc[q4*4+0] = fmaf(w.x, av, acc[q4*4+0]);
                    acc[q4*4+1] = fmaf(w.y, av, acc[q4*4+1]);
                    acc[q4*4+2] = fmaf(w.z, av, acc[q4*4+2]);
                    acc[q4*4+3] = fmaf(w.w, av, acc[q4*4+3]);
                }
            }
        #pragma unroll
        for (int k = 0; k < 16; ++k) {
            float val = acc[k] * s_inv[k] + s_off[k];
            s_g[k][a][bb] = in ? fmaxf(val, 0.f) : 0.f;
        }
    }
    __syncthreads();

    if (tid < 256) {
        int a = tid / 16, bb = tid % 16;
        int gi = i0 + a, gj = j0 + bb;
        float acc[8];
        #pragma unroll
        for (int k = 0; k < 8; ++k) acc[k] = s_b2[k];
        for (int ci = 0; ci < 16; ++ci)
            #pragma unroll
            for (int t9 = 0; t9 < 9; ++t9) {
                float av = s_g[ci][a + t9 / 3][bb + t9 % 3];
                #pragma unroll
                for (int q4 = 0; q4 < 2; ++q4) {
                    const float4 w = *(const float4*)&s_wg2[ci][t9][q4 * 4];
                    acc[q4*4+0] = fmaf(w.x, av, acc[q4*4+0]);
                    acc[q4*4+1] = fmaf(w.y, av, acc[q4*4+1]);
                    acc[q4*4+2] = fmaf(w.z, av, acc[q4*4+2]);
                    acc[q4*4+3] = fmaf(w.w, av, acc[q4*4+3]);
                }
            }
        #pragma unroll
        for (int k = 0; k < 8; ++k)
            guid[(((size_t)b * 8 + k) * HH + gi) * WW + gj] = sigmoidf_(acc[k]);
    }
}

// ---------------------------------------------------------------------------
// Z = cb1 + conv(guidance, cw1[:,4:12]); channel-planar [b][32][H][W].
// zmode=2: f32, zmode=1: bf16.
// ---------------------------------------------------------------------------
__global__ __launch_bounds__(256) void z_kernel(
    const float* __restrict__ guid, const float* __restrict__ cw1,
    const float* __restrict__ cb1, float* __restrict__ Zf,
    unsigned short* __restrict__ Zh, const int zmode)
{
    __shared__ __align__(16) float s_wg[8][9][32];
    __shared__ float s_gub[8][18][20];
    __shared__ float s_b1[32];

    const int tid = threadIdx.x;
    const int b  = blockIdx.z;
    const int i0 = blockIdx.y * TT, j0 = blockIdx.x * TT;

    for (int e = tid; e < 2304; e += 256) {
        int co = e % 32, t = (e / 32) % 9, g = e / 288;
        s_wg[g][t][co] = cw1[(co * 12 + 4 + g) * 9 + t];
    }
    if (tid < 32) s_b1[tid] = cb1[tid];
    for (int e = tid; e < 2592; e += 256) {
        int g = e / 324, q = e % 324, a = q / 18, bb = q % 18;
        int gi = i0 + a - 1, gj = j0 + bb - 1;
        bool in = (gi >= 0 && gi < HH && gj >= 0 && gj < WW);
        s_gub[g][a][bb] = in ? guid[(((size_t)b * 8 + g) * HH + gi) * WW + gj] : 0.f;
    }
    __syncthreads();

    const int a = tid / 16, bb = tid % 16;
    const int gi = i0 + a, gj = j0 + bb;
    float acc[32];
    #pragma unroll
    for (int k = 0; k < 32; ++k) acc[k] = s_b1[k];

    for (int g = 0; g < 8; ++g)
        #pragma unroll
        for (int t9 = 0; t9 < 9; ++t9) {
            float av = s_gub[g][a + t9 / 3][bb + t9 % 3];
            #pragma unroll
            for (int q4 = 0; q4 < 8; ++q4) {
                const float4 w = *(const float4*)&s_wg[g][t9][q4 * 4];
                acc[q4*4+0] = fmaf(w.x, av, acc[q4*4+0]);
                acc[q4*4+1] = fmaf(w.y, av, acc[q4*4+1]);
                acc[q4*4+2] = fmaf(w.z, av, acc[q4*4+2]);
                acc[q4*4+3] = fmaf(w.w, av, acc[q4*4+3]);
            }
        }

    if (zmode == 2) {
        #pragma unroll
        for (int k = 0; k < 32; ++k)
            Zf[(((size_t)b * 32 + k) * HH + gi) * WW + gj] = acc[k];
    } else {
        #pragma unroll
        for (int k = 0; k < 32; ++k) {
            __hip_bfloat16 h = __float2bfloat16(acc[k]);
            unsigned short u; __builtin_memcpy(&u, &h, 2);
            Zh[(((size_t)b * 32 + k) * HH + gi) * WW + gj] = u;
        }
    }
}

// ---------------------------------------------------------------------------
// Fused diffusion iteration, MFMA bf16 (16x16x32) for conv1/conv2/conv3.
// ZM: 0 = no Z (guidance in-kernel), 1 = Z bf16 planar, 2 = Z f32 planar.
// 16x16 out tile/block, 256 threads (4 waves), M-tiles = 2rows x 8cols.
// ---------------------------------------------------------------------------
template <int ZM>
__global__ __launch_bounds__(BSI) void iter_kernel(
    const float* __restrict__ xin, float* __restrict__ xout,
    const float* __restrict__ Zf, const unsigned short* __restrict__ Zh,
    const float* __restrict__ guid,
    const float* __restrict__ cw1, const float* __restrict__ cb1,
    const float* __restrict__ cw2, const float* __restrict__ cb2,
    const float* __restrict__ cw3, const float* __restrict__ cb3)
{
    // LDS map (bytes):
    //  s_x f32[24][24]                      @0      (2304)
    //  ACT: ZM>=1 grads bf16[22][22][4]     @2304   (3872)   | ZM0: [22][22][16] (15488)
    //  C1:  bf16 planes [4][20][20][8]      @6176 (ZM0 @17792) (25600)
    //  U:   union { w1|w2|w3 } / { c2[2][18][18][8] bf16 (10368) + c3 f32[256][4] (4096) }
    constexpr int ACT = 2304;
    constexpr int C1  = (ZM == 0) ? 17792 : 6176;
    constexpr int U   = (ZM == 0) ? 43392 : 31776;
    constexpr int W1  = U;
    constexpr int W2  = (ZM == 0) ? U + 10240 : U + 4096;
    constexpr int W3  = (ZM == 0) ? U + 19456 : U + 13312;
    constexpr int C2  = U;
    constexpr int C3  = U + 10368;
    constexpr int TOT = (ZM == 0) ? 64448 : 46688;

    __shared__ __align__(16) char S[TOT];
    float* s_x = (float*)S;

    const int tid = threadIdx.x;
    const int bz = blockIdx.z;
    const int i0 = blockIdx.y * TT, j0 = blockIdx.x * TT;
    const int o = i0 - 4, p = j0 - 4;
    const float* xb = xin + (size_t)bz * HH * WW;
    // column-interior block: all Z columns [j0-2, j0+17] in-image
    const bool jfast = (j0 != 0) && (j0 != WW - TT);

    // ---- phase 0: stage weights (bf16, fragment layouts) + x tile ----
    if constexpr (ZM >= 1) {
        // w1lds [32 co][64 k], k=tap*4+ch (taps 0..8, ch 0..3), k>=36 zero
        for (int e = tid; e < 1024; e += BSI) {
            int k = (e * 2) & 63, co = e >> 5;
            float f0 = 0.f, f1 = 0.f;
            if (k < 36)     { int tp = k / 4, ch = k & 3; f0 = cw1[(co * 12 + ch) * 9 + tp]; }
            if (k + 1 < 36) { int tp = (k + 1) / 4, ch = (k + 1) & 3; f1 = cw1[(co * 12 + ch) * 9 + tp]; }
            *(unsigned*)&S[W1 + e * 4] = pack2bf(f0, f1);
        }
    } else {
        // w1lds [32 co][160 k], k=tap*16+ch (ch 0..11 real, 12..15 zero; k>=144 zero)
        for (int e = tid; e < 2560; e += BSI) {
            int k = (e * 2) % 160, co = e / 80;
            float f0 = 0.f, f1 = 0.f;
            if (k < 144) {
                int tp = k / 16, ch = k & 15;
                if (ch < 12) f0 = cw1[(co * 12 + ch) * 9 + tp];
                int ch1 = (k + 1) & 15;
                if (ch1 < 12) f1 = cw1[(co * 12 + ch1) * 9 + tp];
            }
            *(unsigned*)&S[W1 + e * 4] = pack2bf(f0, f1);
        }
    }
    // w2lds [9 tap][16 co][32 ch]
    for (int e = tid; e < 2304; e += BSI) {
        int ch = (e * 2) & 31, co = (e >> 4) & 15, tp = e >> 8;
        float f0 = cw2[(co * 32 + ch) * 9 + tp];
        float f1 = cw2[(co * 32 + ch + 1) * 9 + tp];
        *(unsigned*)&S[W2 + e * 4] = pack2bf(f0, f1);
    }
    // w3lds [5 row][160 k], row 0..3 = co, row4 zeros; k=tap*16+ci, k>=144 zero
    for (int e = tid; e < 400; e += BSI) {
        int k = (e * 2) % 160, row = e / 80;
        float f0 = 0.f, f1 = 0.f;
        if (row < 4 && k < 144) {
            int tp = k / 16, ci = k & 15;
            f0 = cw3[(row * 16 + ci) * 9 + tp];
            int ci1 = (k + 1) & 15;
            if (k + 1 < 144) f1 = cw3[(row * 16 + ci1) * 9 + tp];
        }
        *(unsigned*)&S[W3 + e * 4] = pack2bf(f0, f1);
    }
    // x tile (clamped: edge-pad semantics for diffusion gradients)
    for (int e = tid; e < 576; e += BSI) {
        int r = e / 24, c = e % 24;
        int gi = min(max(o + r, 0), HH - 1);
        int gj = min(max(p + c, 0), WW - 1);
        s_x[e] = xb[gi * WW + gj];
    }
    __syncthreads();   // B1: weights + x staged

    const int lane = tid & 63;
    const int g = lane >> 4;
    const int col = lane & 15;
    const int wv = tid >> 6;

    // per-lane bias preloads
    float bias2_v = cb2[col];
    float bias3_v = (col < 4) ? cb3[col] : 0.f;
    float b1v0 = 0.f, b1v1 = 0.f;
    if constexpr (ZM == 0) { b1v0 = cb1[col]; b1v1 = cb1[col + 16]; }

    // B-fragment loads (held in VGPRs for the whole kernel)
    s16x8 fw2[9], fw3[5];
    #pragma unroll
    for (int t = 0; t < 9; ++t)
        fw2[t] = *(const s16x8*)&S[W2 + ((t * 16 + col) * 32 + g * 8) * 2];
    {
        int w3r = col < 4 ? col : 4;
        #pragma unroll
        for (int q = 0; q < 5; ++q)
            fw3[q] = *(const s16x8*)&S[W3 + w3r * 320 + (q * 32 + g * 8) * 2];
    }
    s16x8 fw1[(ZM == 0) ? 10 : 4];
    if constexpr (ZM >= 1) {
        #pragma unroll
        for (int h = 0; h < 2; ++h)
            #pragma unroll
            for (int mf = 0; mf < 2; ++mf)
                fw1[h * 2 + mf] = *(const s16x8*)&S[W1 + (col + 16 * h) * 128 + (mf * 32 + g * 8) * 2];
    } else {
        #pragma unroll
        for (int q = 0; q < 5; ++q)
            #pragma unroll
            for (int h = 0; h < 2; ++h)
                fw1[q * 2 + h] = *(const s16x8*)&S[W1 + (col + 16 * h) * 320 + (q * 32 + g * 8) * 2];
    }

    // ---- gradients (edge-clamped diffs; 0 off-image), rel [1,23) ----
    for (int e = tid; e < 484; e += BSI) {
        int r = e / 22, c = e % 22;
        int gi = o + 1 + r, gj = p + 1 + c;
        bool in = ((unsigned)gi < (unsigned)HH) && ((unsigned)gj < (unsigned)WW);
        float v  = s_x[(r + 1) * 24 + c + 1];
        float gN = s_x[(r + 0) * 24 + c + 1] - v;
        float gS = s_x[(r + 2) * 24 + c + 1] - v;
        float gE = s_x[(r + 1) * 24 + c + 2] - v;
        float gW = s_x[(r + 1) * 24 + c + 0] - v;
        if (!in) { gN = gS = gE = gW = 0.f; }
        if constexpr (ZM >= 1) {
            *(uint2*)&S[ACT + (r * 22 + c) * 8] = make_uint2(pack2bf(gN, gS), pack2bf(gE, gW));
        } else {
            float gv[8];
            #pragma unroll
            for (int k = 0; k < 8; ++k)
                gv[k] = in ? guid[(((size_t)bz * 8 + k) * HH + gi) * WW + gj] : 0.f;
            char* base = &S[ACT + (r * 22 + c) * 32];
            *(uint2*)(base + 0)  = make_uint2(pack2bf(gN, gS), pack2bf(gE, gW));
            *(uint2*)(base + 8)  = make_uint2(pack2bf(gv[0], gv[1]), pack2bf(gv[2], gv[3]));
            *(uint2*)(base + 16) = make_uint2(pack2bf(gv[4], gv[5]), pack2bf(gv[6], gv[7]));
            *(uint2*)(base + 24) = make_uint2(0u, 0u);
        }
    }
    __syncthreads();   // B2: grads ready; frags loaded -> U region reusable

    // ---- conv1 -> c1 planes (30 M-tiles: 10 bands x cols {0,8,12}) ----
    if constexpr (ZM >= 1) {
        const int t0 = 2 * g, t1 = t0 + 1;
        const int dr0 = t0 / 3, dc0 = t0 % 3, dr1 = t1 / 3, dc1 = t1 % 3;
        for (int t = wv; t < 30; t += 4) {
            int band = t / 3, m3 = t % 3;
            int tc = m3 * 8 - (m3 >> 1) * 4;          // {0,8,12}
            int prA = band * 2 + (col >> 3), pcA = tc + (col & 7);
            s16x4 a0 = *(const s16x4*)&S[ACT + ((prA + dr0) * 22 + (pcA + dc0)) * 8];
            s16x4 a1 = *(const s16x4*)&S[ACT + ((prA + dr1) * 22 + (pcA + dc1)) * 8];
            s16x4 a2 = *(const s16x4*)&S[ACT + ((prA + 2) * 22 + (pcA + 2)) * 8];   // tap8=(2,2)
            s16x8 A1 = __builtin_shufflevector(a0, a1, 0, 1, 2, 3, 4, 5, 6, 7);
            s16x8 A2 = __builtin_shufflevector(a2, a2, 0, 1, 2, 3, 0, 1, 2, 3);
            int prD = band * 2 + (g >> 1);
            int pc0 = tc + ((4 * g) & 7);
            int giD = o + 2 + prD;
            int gzi = min(max(giD, 0), HH - 1);
            bool rin = (unsigned)giD < (unsigned)HH;
            int gjD = p + 2 + pc0;
            #pragma unroll
            for (int h = 0; h < 2; ++h) {
                int co = col + 16 * h;
                size_t zrow = ((size_t)((bz * 32 + co) * HH + gzi)) * WW;
                f32x4 acc;
                if (jfast) {
                    if constexpr (ZM == 2) {
                        float2 z0 = *(const float2*)(Zf + zrow + gjD);
                        float2 z1 = *(const float2*)(Zf + zrow + gjD + 2);
                        acc[0] = z0.x; acc[1] = z0.y; acc[2] = z1.x; acc[3] = z1.y;
                    } else {
                        unsigned u0 = *(const unsigned*)(Zh + zrow + gjD);
                        unsigned u1 = *(const unsigned*)(Zh + zrow + gjD + 2);
                        acc[0] = bfbits2f(u0 & 0xffffu); acc[1] = bfbits2f(u0 >> 16);
                        acc[2] = bfbits2f(u1 & 0xffffu); acc[3] = bfbits2f(u1 >> 16);
                    }
                } else {
                    // edge column-block: per-element bounds-checked loads
                    #pragma unroll
                    for (int i = 0; i < 4; ++i) {
                        int gj = gjD + i;
                        bool cin = (unsigned)gj < (unsigned)WW;
                        if constexpr (ZM == 2) acc[i] = cin ? Zf[zrow + gj] : 0.f;
                        else                   acc[i] = cin ? bfbits2f(Zh[zrow + gj]) : 0.f;
                    }
                }
                acc = MFMA16(A1, fw1[h * 2 + 0], acc, 0, 0, 0);
                acc = MFMA16(A2, fw1[h * 2 + 1], acc, 0, 0, 0);
                #pragma unroll
                for (int i = 0; i < 4; ++i) {
                    int pcD = pc0 + i;
                    bool in = rin && ((unsigned)(p + 2 + pcD) < (unsigned)WW);
                    float v = in ? fmaxf(acc[i], 0.f) : 0.f;
                    *(short*)&S[C1 + (co >> 3) * 6400 + (prD * 20 + pcD) * 16 + (co & 7) * 2] = f2bf(v);
                }
            }
        }
    } else {
        for (int t = wv; t < 30; t += 4) {
            int band = t / 3, m3 = t % 3;
            int tc = m3 * 8 - (m3 >> 1) * 4;
            int prA = band * 2 + (col >> 3), pcA = tc + (col & 7);
            s16x8 Aq[5];
            #pragma unroll
            for (int q = 0; q < 5; ++q) {
                int tp = 2 * q + (g >> 1); if (tp > 8) tp = 8;
                int dr = tp / 3, dc = tp % 3;
                Aq[q] = *(const s16x8*)&S[ACT + ((prA + dr) * 22 + (pcA + dc)) * 32 + (g & 1) * 16];
            }
            int prD = band * 2 + (g >> 1);
            int pc0 = tc + ((4 * g) & 7);
            int giD = o + 2 + prD;
            bool rin = (unsigned)giD < (unsigned)HH;
            #pragma unroll
            for (int h = 0; h < 2; ++h) {
                int co = col + 16 * h;
                float bi = h ? b1v1 : b1v0;
                f32x4 acc = {bi, bi, bi, bi};
                #pragma unroll
                for (int q = 0; q < 5; ++q)
                    acc = MFMA16(Aq[q], fw1[q * 2 + h], acc, 0, 0, 0);
                #pragma unroll
                for (int i = 0; i < 4; ++i) {
                    int pcD = pc0 + i;
                    bool in = rin && ((unsigned)(p + 2 + pcD) < (unsigned)WW);
                    float v = in ? fmaxf(acc[i], 0.f) : 0.f;
                    *(short*)&S[C1 + (co >> 3) * 6400 + (prD * 20 + pcD) * 16 + (co & 7) * 2] = f2bf(v);
                }
            }
        }
    }
    __syncthreads();   // B3: c1 ready (U region now free -> c2/c3)

    // ---- conv2 -> c2 planes (27 M-tiles: 9 bands x cols {0,8,10}) ----
    for (int t = wv; t < 27; t += 4) {
        int band = t / 3, m3 = t % 3;
        int tc = m3 * 8 - (m3 >> 1) * 6;              // {0,8,10}
        int prA = band * 2 + (col >> 3), pcA = tc + (col & 7);
        f32x4 acc = {0.f, 0.f, 0.f, 0.f};
        #pragma unroll
        for (int tp = 0; tp < 9; ++tp) {
            int dr = tp / 3, dc = tp % 3;
            s16x8 Af = *(const s16x8*)&S[C1 + g * 6400 + ((prA + dr) * 20 + (pcA + dc)) * 16];
            acc = MFMA16(Af, fw2[tp], acc, 0, 0, 0);
        }
        int prD = band * 2 + (g >> 1);
        int pc0 = tc + ((4 * g) & 7);
        bool rin = (unsigned)(o + 3 + prD) < (unsigned)HH;
        #pragma unroll
        for (int i = 0; i < 4; ++i) {
            int pcD = pc0 + i;
            bool in = rin && ((unsigned)(p + 3 + pcD) < (unsigned)WW);
            float v = in ? fmaxf(acc[i] + bias2_v, 0.f) : 0.f;
            *(short*)&S[C2 + (col >> 3) * 5184 + (prD * 18 + pcD) * 16 + (col & 7) * 2] = f2bf(v);
        }
    }
    __syncthreads();   // B4: c2 ready

    // ---- conv3 -> c3 (16 M-tiles: 8 bands x cols {0,8}; K=144->160, 5 mfma) ----
    for (int t = wv; t < 16; t += 4) {
        int band = t >> 1, tc = (t & 1) * 8;
        int rA = band * 2 + (col >> 3), cA = tc + (col & 7);
        f32x4 acc = {0.f, 0.f, 0.f, 0.f};
        #pragma unroll
        for (int q = 0; q < 5; ++q) {
            int tp = 2 * q + (g >> 1); if (tp > 8) tp = 8;
            int dr = tp / 3, dc = tp % 3;
            int half = g & 1;
            s16x8 Af = *(const s16x8*)&S[C2 + half * 5184 + ((rA + dr) * 18 + (cA + dc)) * 16];
            acc = MFMA16(Af, fw3[q], acc, 0, 0, 0);
        }
        if (col < 4) {
            int rD = band * 2 + (g >> 1), c0 = tc + ((4 * g) & 7);
            #pragma unroll
            for (int i = 0; i < 4; ++i)
                *(float*)&S[C3 + ((rD * 16 + c0 + i) * 4 + col) * 4] = acc[i] + bias3_v;
        }
    }
    __syncthreads();   // B5: c3 ready

    // ---- conv3 sigmoid + diffusion update (f32) ----
    {
        int r = tid >> 4, c = tid & 15;
        f32x4 cc = *(const f32x4*)&S[C3 + tid * 16];
        float cN = sigmoidf_(cc[0]), cS = sigmoidf_(cc[1]);
        float cE = sigmoidf_(cc[2]), cWd = sigmoidf_(cc[3]);
        float v  = s_x[(r + 4) * 24 + c + 4];
        float gN = s_x[(r + 3) * 24 + c + 4] - v;
        float gS = s_x[(r + 5) * 24 + c + 4] - v;
        float gE = s_x[(r + 4) * 24 + c + 5] - v;
        float gW = s_x[(r + 4) * 24 + c + 3] - v;
        xout[((size_t)bz * HH + (i0 + r)) * WW + (j0 + c)] =
            v + LAMV * (cN * gN + cS * gS + cE * gE + cWd * gW);
    }
}

extern "C" void kernel_launch(void* const* d_in, const int* in_sizes, int n_in,
                              void* d_out, int out_size, void* d_ws, size_t ws_size,
                              hipStream_t stream) {
    (void)in_sizes; (void)n_in; (void)out_size;
    const float* x   = (const float*)d_in[0];
    const float* gw1 = (const float*)d_in[1];
    const float* gb1 = (const float*)d_in[2];
    const float* bng = (const float*)d_in[3];
    const float* bnb = (const float*)d_in[4];
    const float* bnm = (const float*)d_in[5];
    const float* bnv = (const float*)d_in[6];
    const float* gw2 = (const float*)d_in[7];
    const float* gb2 = (const float*)d_in[8];
    const float* cw1 = (const float*)d_in[9];
    const float* cb1 = (const float*)d_in[10];
    const float* cw2 = (const float*)d_in[11];
    const float* cb2 = (const float*)d_in[12];
    const float* cw3 = (const float*)d_in[13];
    const float* cb3 = (const float*)d_in[14];
    float* out = (float*)d_out;

    char* base = (char*)d_ws;
    const size_t PX   = (size_t)NB * HH * WW;
    const size_t Z32B = PX * 32 * 4;   // 256 MiB
    const size_t Z16B = PX * 32 * 2;   // 128 MiB
    const size_t GUB  = PX * 8 * 4;    //  64 MiB
    const size_t XB   = PX * 4;        //   8 MiB

    int zmode;
    if      (ws_size >= Z32B + GUB + XB) zmode = 2;
    else if (ws_size >= Z16B + GUB + XB) zmode = 1;
    else                                 zmode = 0;

    float* Zf = nullptr; unsigned short* Zh = nullptr;
    float *guidp, *bufA;
    if (zmode == 2)      { Zf = (float*)base;          guidp = (float*)(base + Z32B); bufA = (float*)(base + Z32B + GUB); }
    else if (zmode == 1) { Zh = (unsigned short*)base; guidp = (float*)(base + Z16B); bufA = (float*)(base + Z16B + GUB); }
    else                 { guidp = (float*)base;       bufA = (float*)(base + GUB); }

    dim3 grid(WW / TT, HH / TT, NB);
    guidance_kernel<<<grid, BSG, 0, stream>>>(x, gw1, gb1, bng, bnb, bnm, bnv, gw2, gb2, guidp);
    if (zmode)
        z_kernel<<<grid, 256, 0, stream>>>(guidp, cw1, cb1, Zf, Zh, zmode);

    const float* cur = x;
    for (int it = 0; it < 10; ++it) {
        float* dst = (it & 1) ? out : bufA;   // it9 (odd) lands in d_out
        if (zmode == 2)
            iter_kernel<2><<<grid, BSI, 0, stream>>>(cur, dst, Zf, Zh, guidp, cw1, cb1, cw2, cb2, cw3, cb3);
        else if (zmode == 1)
            iter_kernel<1><<<grid, BSI, 0, stream>>>(cur, dst, Zf, Zh, guidp, cw1, cb1, cw2, cb2, cw3, cb3);
        else
            iter_kernel<0><<<grid, BSI, 0, stream>>>(cur, dst, Zf, Zh, guidp, cw1, cb1, cw2, cb2, cw3, cb3);
        cur = dst;
    }
}

// Round 7
// 4053.238 us; speedup vs baseline: 94.8366x; 1.0137x over previous
//
#include <hip/hip_runtime.h>
#include <hip/hip_bf16.h>

#define HH 512
#define WW 512
#define NB 8
#define TT 16
#define BSG 384
#define BSI 256
#define EPSV 1e-5f
#define LAMV 0.1f

typedef __attribute__((ext_vector_type(4))) float f32x4;
typedef __attribute__((ext_vector_type(4))) short s16x4;
typedef __attribute__((ext_vector_type(8))) short s16x8;

#define MFMA16 __builtin_amdgcn_mfma_f32_16x16x32_bf16

// packed-weight blob offsets (bytes)
#define W2PK 0        // [9 tap][16 co][32 ch] bf16   (9216 B)
#define W3PK 9216     // [5 row][160 k] bf16          (1600 B)
#define W1PKZ 10816   // [32 co][64 k] bf16 grad-part (4096 B)
#define W1PKF 14912   // [32 co][160 k] bf16 full     (10240 B)
#define WPKTOT 25152

__device__ __forceinline__ float sigmoidf_(float v) { return 1.0f / (1.0f + __expf(-v)); }

__device__ __forceinline__ short f2bf(float f) {
    __hip_bfloat16 h = __float2bfloat16(f);
    short s; __builtin_memcpy(&s, &h, 2); return s;
}
__device__ __forceinline__ unsigned pack2bf(float a, float b) {
    __hip_bfloat16 ha = __float2bfloat16(a), hb = __float2bfloat16(b);
    unsigned short ua, ub;
    __builtin_memcpy(&ua, &ha, 2); __builtin_memcpy(&ub, &hb, 2);
    return (unsigned)ua | ((unsigned)ub << 16);
}
__device__ __forceinline__ float bfbits2f(unsigned u16) {
    unsigned x = u16 << 16; float f; __builtin_memcpy(&f, &x, 4); return f;
}

// ---------------------------------------------------------------------------
// prep: pack conv weights into fragment-major bf16 blobs (runs once, 1 block)
// ---------------------------------------------------------------------------
__global__ __launch_bounds__(256) void prep_kernel(
    const float* __restrict__ cw1, const float* __restrict__ cw2,
    const float* __restrict__ cw3, unsigned short* __restrict__ wpk)
{
    const int tid = threadIdx.x;
    // W2PK [t][co][ch]
    for (int e = tid; e < 4608; e += 256) {
        int ch = e & 31, co = (e >> 5) & 15, t = e >> 9;
        wpk[W2PK / 2 + e] = (unsigned short)f2bf(cw2[(co * 32 + ch) * 9 + t]);
    }
    // W3PK [row][k], k=tap*16+ci ; row 4 and k>=144 zero
    for (int e = tid; e < 800; e += 256) {
        int k = e % 160, row = e / 160;
        float v = 0.f;
        if (row < 4 && k < 144) { int tp = k / 16, ci = k & 15; v = cw3[(row * 16 + ci) * 9 + tp]; }
        wpk[W3PK / 2 + e] = (unsigned short)f2bf(v);
    }
    // W1PKZ [co][k], k=tap*4+ch (ch 0..3), k>=36 zero
    for (int e = tid; e < 2048; e += 256) {
        int k = e & 63, co = e >> 6;
        float v = 0.f;
        if (k < 36) { int tp = k >> 2, ch = k & 3; v = cw1[(co * 12 + ch) * 9 + tp]; }
        wpk[W1PKZ / 2 + e] = (unsigned short)f2bf(v);
    }
    // W1PKF [co][k], k=tap*16+ch (ch<12 real), k>=144 zero
    for (int e = tid; e < 5120; e += 256) {
        int k = e % 160, co = e / 160;
        float v = 0.f;
        if (k < 144) { int tp = k / 16, ch = k & 15; if (ch < 12) v = cw1[(co * 12 + ch) * 9 + tp]; }
        wpk[W1PKF / 2 + e] = (unsigned short)f2bf(v);
    }
}

// ---------------------------------------------------------------------------
// Guidance: avgpool3 -> dilated conv(1->16)+BN+relu -> conv(16->8)+sigmoid.
// ---------------------------------------------------------------------------
__global__ __launch_bounds__(BSG) void guidance_kernel(
    const float* __restrict__ x, const float* __restrict__ gw1, const float* __restrict__ gb1,
    const float* __restrict__ bng, const float* __restrict__ bnb, const float* __restrict__ bnm,
    const float* __restrict__ bnv, const float* __restrict__ gw2, const float* __restrict__ gb2,
    float* __restrict__ guid)
{
    __shared__ __align__(16) float s_wg1[9][16];
    __shared__ __align__(16) float s_wg2[16][9][8];
    __shared__ float s_inv[16], s_off[16], s_b1[16], s_b2[8];
    __shared__ float s_x[24][25];
    __shared__ float s_xs[22][23];
    __shared__ float s_g[16][18][19];

    const int tid = threadIdx.x;
    const int b  = blockIdx.z;
    const int i0 = blockIdx.y * TT, j0 = blockIdx.x * TT;
    const int o = i0 - 4, p = j0 - 4;
    const float* xb = x + (size_t)b * HH * WW;

    for (int e = tid; e < 144; e += BSG) { int co = e % 16, t = e / 16; s_wg1[t][co] = gw1[co * 9 + t]; }
    for (int e = tid; e < 1152; e += BSG) {
        int co = e % 8, t = (e / 8) % 9, ci = e / 72;
        s_wg2[ci][t][co] = gw2[(co * 16 + ci) * 9 + t];
    }
    if (tid < 16) {
        float iv = bng[tid] * rsqrtf(bnv[tid] + EPSV);
        s_inv[tid] = iv; s_off[tid] = bnb[tid] - bnm[tid] * iv; s_b1[tid] = gb1[tid];
    }
    if (tid < 8) s_b2[tid] = gb2[tid];

    for (int e = tid; e < 576; e += BSG) {
        int r = e / 24, c = e % 24;
        int gi = o + r, gj = p + c;
        float v = 0.f;
        if (gi >= 0 && gi < HH && gj >= 0 && gj < WW) v = xb[gi * WW + gj];
        s_x[r][c] = v;
    }
    __syncthreads();

    for (int e = tid; e < 484; e += BSG) {
        int a = e / 22, bb = e % 22;
        int gi = o + a + 1, gj = p + bb + 1;
        float v = 0.f;
        if (gi >= 0 && gi < HH && gj >= 0 && gj < WW) {
            float s = 0.f;
            #pragma unroll
            for (int dr = 0; dr < 3; ++dr)
                #pragma unroll
                for (int dc = 0; dc < 3; ++dc) s += s_x[a + dr][bb + dc];
            v = s * (1.0f / 9.0f);
        }
        s_xs[a][bb] = v;
    }
    __syncthreads();

    for (int e = tid; e < 324; e += BSG) {
        int a = e / 18, bb = e % 18;
        int gi = o + a + 3, gj = p + bb + 3;
        bool in = (gi >= 0 && gi < HH && gj >= 0 && gj < WW);
        float acc[16];
        #pragma unroll
        for (int k = 0; k < 16; ++k) acc[k] = s_b1[k];
        #pragma unroll
        for (int kh = 0; kh < 3; ++kh)
            #pragma unroll
            for (int kw = 0; kw < 3; ++kw) {
                float av = s_xs[a + 2 * kh][bb + 2 * kw];
                #pragma unroll
                for (int q4 = 0; q4 < 4; ++q4) {
                    const float4 w = *(const float4*)&s_wg1[kh * 3 + kw][q4 * 4];
                    acc[q4*4+0] = fmaf(w.x, av, acc[q4*4+0]);
                    acc[q4*4+1] = fmaf(w.y, av, acc[q4*4+1]);
                    acc[q4*4+2] = fmaf(w.z, av, acc[q4*4+2]);
                    acc[q4*4+3] = fmaf(w.w, av, acc[q4*4+3]);
                }
            }
        #pragma unroll
        for (int k = 0; k < 16; ++k) {
            float val = acc[k] * s_inv[k] + s_off[k];
            s_g[k][a][bb] = in ? fmaxf(val, 0.f) : 0.f;
        }
    }
    __syncthreads();

    if (tid < 256) {
        int a = tid / 16, bb = tid % 16;
        int gi = i0 + a, gj = j0 + bb;
        float acc[8];
        #pragma unroll
        for (int k = 0; k < 8; ++k) acc[k] = s_b2[k];
        for (int ci = 0; ci < 16; ++ci)
            #pragma unroll
            for (int t9 = 0; t9 < 9; ++t9) {
                float av = s_g[ci][a + t9 / 3][bb + t9 % 3];
                #pragma unroll
                for (int q4 = 0; q4 < 2; ++q4) {
                    const float4 w = *(const float4*)&s_wg2[ci][t9][q4 * 4];
                    acc[q4*4+0] = fmaf(w.x, av, acc[q4*4+0]);
                    acc[q4*4+1] = fmaf(w.y, av, acc[q4*4+1]);
                    acc[q4*4+2] = fmaf(w.z, av, acc[q4*4+2]);
                    acc[q4*4+3] = fmaf(w.w, av, acc[q4*4+3]);
                }
            }
        #pragma unroll
        for (int k = 0; k < 8; ++k)
            guid[(((size_t)b * 8 + k) * HH + gi) * WW + gj] = sigmoidf_(acc[k]);
    }
}

// ---------------------------------------------------------------------------
// Z = cb1 + conv(guidance, cw1[:,4:12]); channel-planar [b][32][H][W] bf16.
// ---------------------------------------------------------------------------
__global__ __launch_bounds__(256) void z_kernel(
    const float* __restrict__ guid, const float* __restrict__ cw1,
    const float* __restrict__ cb1, unsigned short* __restrict__ Zh)
{
    __shared__ __align__(16) float s_wg[8][9][32];
    __shared__ float s_gub[8][18][20];
    __shared__ float s_b1[32];

    const int tid = threadIdx.x;
    const int b  = blockIdx.z;
    const int i0 = blockIdx.y * TT, j0 = blockIdx.x * TT;

    for (int e = tid; e < 2304; e += 256) {
        int co = e % 32, t = (e / 32) % 9, g = e / 288;
        s_wg[g][t][co] = cw1[(co * 12 + 4 + g) * 9 + t];
    }
    if (tid < 32) s_b1[tid] = cb1[tid];
    for (int e = tid; e < 2592; e += 256) {
        int g = e / 324, q = e % 324, a = q / 18, bb = q % 18;
        int gi = i0 + a - 1, gj = j0 + bb - 1;
        bool in = (gi >= 0 && gi < HH && gj >= 0 && gj < WW);
        s_gub[g][a][bb] = in ? guid[(((size_t)b * 8 + g) * HH + gi) * WW + gj] : 0.f;
    }
    __syncthreads();

    const int a = tid / 16, bb = tid % 16;
    const int gi = i0 + a, gj = j0 + bb;
    float acc[32];
    #pragma unroll
    for (int k = 0; k < 32; ++k) acc[k] = s_b1[k];

    for (int g = 0; g < 8; ++g)
        #pragma unroll
        for (int t9 = 0; t9 < 9; ++t9) {
            float av = s_gub[g][a + t9 / 3][bb + t9 % 3];
            #pragma unroll
            for (int q4 = 0; q4 < 8; ++q4) {
                const float4 w = *(const float4*)&s_wg[g][t9][q4 * 4];
                acc[q4*4+0] = fmaf(w.x, av, acc[q4*4+0]);
                acc[q4*4+1] = fmaf(w.y, av, acc[q4*4+1]);
                acc[q4*4+2] = fmaf(w.z, av, acc[q4*4+2]);
                acc[q4*4+3] = fmaf(w.w, av, acc[q4*4+3]);
            }
        }

    #pragma unroll
    for (int k = 0; k < 32; ++k)
        Zh[(((size_t)b * 32 + k) * HH + gi) * WW + gj] = (unsigned short)f2bf(acc[k]);
}

// ---------------------------------------------------------------------------
// Fused diffusion iteration, MFMA bf16 16x16x32.
// ZM: 0 = recompute guidance part (guid f32 planar), 1 = Z bf16 planar.
// Weights read as fragments straight from packed global blob (L1/L2-hot).
// LDS (ZM1): s_x 2304 | ACT grads [22][22][4]bf16 3872 | C1 [4][20][21s][8]
//   26880 | C2 [2][18][19s][8] 10944 | C3 f32[256][4] aliases C1. TOT 44000.
// Padded strides (21/19 slots) kill the 8-way bank conflicts on A-frag reads.
// ---------------------------------------------------------------------------
template <int ZM>
__global__ __launch_bounds__(BSI) void iter_kernel(
    const float* __restrict__ xin, float* __restrict__ xout,
    const unsigned short* __restrict__ Zh, const float* __restrict__ guid,
    const unsigned short* __restrict__ wpk, const float* __restrict__ cb1,
    const float* __restrict__ cb2, const float* __restrict__ cb3)
{
    constexpr int ACT = 2304;
    constexpr int C1  = (ZM == 0) ? 17792 : 6176;        // base of c1 planes
    constexpr int C2  = (ZM == 0) ? 44672 : 33056;
    constexpr int C3  = C1;                              // aliases dead C1
    constexpr int TOT = (ZM == 0) ? 55616 : 44000;
    constexpr int C1P = 6720;                            // plane stride (B)
    constexpr int C2P = 5472;

    __shared__ __align__(16) char S[TOT];
    float* s_x = (float*)S;

    const int tid = threadIdx.x;
    const int bz = blockIdx.z;
    const int i0 = blockIdx.y * TT, j0 = blockIdx.x * TT;
    const int o = i0 - 4, p = j0 - 4;
    const float* xb = xin + (size_t)bz * HH * WW;
    const bool jfast = (j0 != 0) && (j0 != WW - TT);

    // ---- stage x tile (clamped: edge-pad semantics) ----
    for (int e = tid; e < 576; e += BSI) {
        int r = e / 24, c = e % 24;
        int gi = min(max(o + r, 0), HH - 1);
        int gj = min(max(p + c, 0), WW - 1);
        s_x[e] = xb[gi * WW + gj];
    }

    const int lane = tid & 63;
    const int g = lane >> 4;
    const int col = lane & 15;
    const int wv = tid >> 6;

    // per-lane biases
    float bias2_v = cb2[col];
    float bias3_v = (col < 4) ? cb3[col] : 0.f;
    float b1v0 = 0.f, b1v1 = 0.f;
    if constexpr (ZM == 0) { b1v0 = cb1[col]; b1v1 = cb1[col + 16]; }

    // B-fragments: coalesced loads from packed global blob
    s16x8 fw2[9], fw3[5];
    #pragma unroll
    for (int t = 0; t < 9; ++t)
        fw2[t] = *(const s16x8*)&wpk[W2PK / 2 + (t * 16 + col) * 32 + g * 8];
    {
        int w3r = col < 4 ? col : 4;
        #pragma unroll
        for (int q = 0; q < 5; ++q)
            fw3[q] = *(const s16x8*)&wpk[W3PK / 2 + w3r * 160 + q * 32 + g * 8];
    }
    s16x8 fw1[(ZM == 0) ? 10 : 4];
    if constexpr (ZM == 1) {
        #pragma unroll
        for (int h = 0; h < 2; ++h)
            #pragma unroll
            for (int mf = 0; mf < 2; ++mf)
                fw1[h * 2 + mf] = *(const s16x8*)&wpk[W1PKZ / 2 + (col + 16 * h) * 64 + mf * 32 + g * 8];
    } else {
        #pragma unroll
        for (int q = 0; q < 5; ++q)
            #pragma unroll
            for (int h = 0; h < 2; ++h)
                fw1[q * 2 + h] = *(const s16x8*)&wpk[W1PKF / 2 + (col + 16 * h) * 160 + q * 32 + g * 8];
    }
    __syncthreads();   // B1: s_x staged

    // ---- gradients (edge-clamped diffs; 0 off-image), rel [1,23) ----
    for (int e = tid; e < 484; e += BSI) {
        int r = e / 22, c = e % 22;
        int gi = o + 1 + r, gj = p + 1 + c;
        bool in = ((unsigned)gi < (unsigned)HH) && ((unsigned)gj < (unsigned)WW);
        float v  = s_x[(r + 1) * 24 + c + 1];
        float gN = s_x[(r + 0) * 24 + c + 1] - v;
        float gS = s_x[(r + 2) * 24 + c + 1] - v;
        float gE = s_x[(r + 1) * 24 + c + 2] - v;
        float gW = s_x[(r + 1) * 24 + c + 0] - v;
        if (!in) { gN = gS = gE = gW = 0.f; }
        if constexpr (ZM == 1) {
            *(uint2*)&S[ACT + (r * 22 + c) * 8] = make_uint2(pack2bf(gN, gS), pack2bf(gE, gW));
        } else {
            float gv[8];
            #pragma unroll
            for (int k = 0; k < 8; ++k)
                gv[k] = in ? guid[(((size_t)bz * 8 + k) * HH + gi) * WW + gj] : 0.f;
            char* base = &S[ACT + (r * 22 + c) * 32];
            *(uint2*)(base + 0)  = make_uint2(pack2bf(gN, gS), pack2bf(gE, gW));
            *(uint2*)(base + 8)  = make_uint2(pack2bf(gv[0], gv[1]), pack2bf(gv[2], gv[3]));
            *(uint2*)(base + 16) = make_uint2(pack2bf(gv[4], gv[5]), pack2bf(gv[6], gv[7]));
            *(uint2*)(base + 24) = make_uint2(0u, 0u);
        }
    }
    __syncthreads();   // B2: grads ready

    // ---- conv1 -> c1 planes (30 M-tiles: 10 bands x cols {0,8,12}) ----
    if constexpr (ZM == 1) {
        const int t0 = 2 * g, t1 = t0 + 1;
        const int dr0 = t0 / 3, dc0 = t0 % 3, dr1 = t1 / 3, dc1 = t1 % 3;
        for (int t = wv; t < 30; t += 4) {
            int band = t / 3, m3 = t % 3;
            int tc = m3 * 8 - (m3 >> 1) * 4;          // {0,8,12}
            int prA = band * 2 + (col >> 3), pcA = tc + (col & 7);
            s16x4 a0 = *(const s16x4*)&S[ACT + ((prA + dr0) * 22 + (pcA + dc0)) * 8];
            s16x4 a1 = *(const s16x4*)&S[ACT + ((prA + dr1) * 22 + (pcA + dc1)) * 8];
            s16x4 a2 = *(const s16x4*)&S[ACT + ((prA + 2) * 22 + (pcA + 2)) * 8];   // tap8
            s16x8 A1 = __builtin_shufflevector(a0, a1, 0, 1, 2, 3, 4, 5, 6, 7);
            s16x8 A2 = __builtin_shufflevector(a2, a2, 0, 1, 2, 3, 0, 1, 2, 3);
            int prD = band * 2 + (g >> 1);
            int pc0 = tc + ((4 * g) & 7);
            int giD = o + 2 + prD;
            int gzi = min(max(giD, 0), HH - 1);
            bool rin = (unsigned)giD < (unsigned)HH;
            int gjD = p + 2 + pc0;
            #pragma unroll
            for (int h = 0; h < 2; ++h) {
                int co = col + 16 * h;
                size_t zrow = ((size_t)((bz * 32 + co) * HH + gzi)) * WW;
                f32x4 acc;
                if (jfast) {
                    unsigned u0 = *(const unsigned*)(Zh + zrow + gjD);
                    unsigned u1 = *(const unsigned*)(Zh + zrow + gjD + 2);
                    acc[0] = bfbits2f(u0 & 0xffffu); acc[1] = bfbits2f(u0 >> 16);
                    acc[2] = bfbits2f(u1 & 0xffffu); acc[3] = bfbits2f(u1 >> 16);
                } else {
                    #pragma unroll
                    for (int i = 0; i < 4; ++i) {
                        int gj = gjD + i;
                        bool cin = (unsigned)gj < (unsigned)WW;
                        acc[i] = cin ? bfbits2f(Zh[zrow + gj]) : 0.f;
                    }
                }
                acc = MFMA16(A1, fw1[h * 2 + 0], acc, 0, 0, 0);
                acc = MFMA16(A2, fw1[h * 2 + 1], acc, 0, 0, 0);
                #pragma unroll
                for (int i = 0; i < 4; ++i) {
                    int pcD = pc0 + i;
                    bool in = rin && ((unsigned)(p + 2 + pcD) < (unsigned)WW);
                    float v = in ? fmaxf(acc[i], 0.f) : 0.f;
                    *(short*)&S[C1 + (co >> 3) * C1P + (prD * 21 + pcD) * 16 + (co & 7) * 2] = f2bf(v);
                }
            }
        }
    } else {
        for (int t = wv; t < 30; t += 4) {
            int band = t / 3, m3 = t % 3;
            int tc = m3 * 8 - (m3 >> 1) * 4;
            int prA = band * 2 + (col >> 3), pcA = tc + (col & 7);
            s16x8 Aq[5];
            #pragma unroll
            for (int q = 0; q < 5; ++q) {
                int tp = 2 * q + (g >> 1); if (tp > 8) tp = 8;
                int dr = tp / 3, dc = tp % 3;
                Aq[q] = *(const s16x8*)&S[ACT + ((prA + dr) * 22 + (pcA + dc)) * 32 + (g & 1) * 16];
            }
            int prD = band * 2 + (g >> 1);
            int pc0 = tc + ((4 * g) & 7);
            int giD = o + 2 + prD;
            bool rin = (unsigned)giD < (unsigned)HH;
            #pragma unroll
            for (int h = 0; h < 2; ++h) {
                int co = col + 16 * h;
                float bi = h ? b1v1 : b1v0;
                f32x4 acc = {bi, bi, bi, bi};
                #pragma unroll
                for (int q = 0; q < 5; ++q)
                    acc = MFMA16(Aq[q], fw1[q * 2 + h], acc, 0, 0, 0);
                #pragma unroll
                for (int i = 0; i < 4; ++i) {
                    int pcD = pc0 + i;
                    bool in = rin && ((unsigned)(p + 2 + pcD) < (unsigned)WW);
                    float v = in ? fmaxf(acc[i], 0.f) : 0.f;
                    *(short*)&S[C1 + (co >> 3) * C1P + (prD * 21 + pcD) * 16 + (co & 7) * 2] = f2bf(v);
                }
            }
        }
    }
    __syncthreads();   // B3: c1 ready

    // ---- conv2 -> c2 planes (27 M-tiles: 9 bands x cols {0,8,10}) ----
    for (int t = wv; t < 27; t += 4) {
        int band = t / 3, m3 = t % 3;
        int tc = m3 * 8 - (m3 >> 1) * 6;              // {0,8,10}
        int prA = band * 2 + (col >> 3), pcA = tc + (col & 7);
        f32x4 acc = {0.f, 0.f, 0.f, 0.f};
        #pragma unroll
        for (int tp = 0; tp < 9; ++tp) {
            int dr = tp / 3, dc = tp % 3;
            s16x8 Af = *(const s16x8*)&S[C1 + g * C1P + ((prA + dr) * 21 + (pcA + dc)) * 16];
            acc = MFMA16(Af, fw2[tp], acc, 0, 0, 0);
        }
        int prD = band * 2 + (g >> 1);
        int pc0 = tc + ((4 * g) & 7);
        bool rin = (unsigned)(o + 3 + prD) < (unsigned)HH;
        #pragma unroll
        for (int i = 0; i < 4; ++i) {
            int pcD = pc0 + i;
            bool in = rin && ((unsigned)(p + 3 + pcD) < (unsigned)WW);
            float v = in ? fmaxf(acc[i] + bias2_v, 0.f) : 0.f;
            *(short*)&S[C2 + (col >> 3) * C2P + (prD * 19 + pcD) * 16 + (col & 7) * 2] = f2bf(v);
        }
    }
    __syncthreads();   // B4: c2 ready, c1 dead (C3 may overwrite)

    // ---- conv3 -> c3 (16 M-tiles; K=144->160, 5 mfma) ----
    for (int t = wv; t < 16; t += 4) {
        int band = t >> 1, tc = (t & 1) * 8;
        int rA = band * 2 + (col >> 3), cA = tc + (col & 7);
        f32x4 acc = {0.f, 0.f, 0.f, 0.f};
        #pragma unroll
        for (int q = 0; q < 5; ++q) {
            int tp = 2 * q + (g >> 1); if (tp > 8) tp = 8;
            int dr = tp / 3, dc = tp % 3;
            int half = g & 1;
            s16x8 Af = *(const s16x8*)&S[C2 + half * C2P + ((rA + dr) * 19 + (cA + dc)) * 16];
            acc = MFMA16(Af, fw3[q], acc, 0, 0, 0);
        }
        if (col < 4) {
            int rD = band * 2 + (g >> 1), c0 = tc + ((4 * g) & 7);
            #pragma unroll
            for (int i = 0; i < 4; ++i)
                *(float*)&S[C3 + ((rD * 16 + c0 + i) * 4 + col) * 4] = acc[i] + bias3_v;
        }
    }
    __syncthreads();   // B5: c3 ready

    // ---- sigmoid + diffusion update (f32) ----
    {
        int r = tid >> 4, c = tid & 15;
        f32x4 cc = *(const f32x4*)&S[C3 + tid * 16];
        float cN = sigmoidf_(cc[0]), cS = sigmoidf_(cc[1]);
        float cE = sigmoidf_(cc[2]), cWd = sigmoidf_(cc[3]);
        float v  = s_x[(r + 4) * 24 + c + 4];
        float gN = s_x[(r + 3) * 24 + c + 4] - v;
        float gS = s_x[(r + 5) * 24 + c + 4] - v;
        float gE = s_x[(r + 4) * 24 + c + 5] - v;
        float gW = s_x[(r + 4) * 24 + c + 3] - v;
        xout[((size_t)bz * HH + (i0 + r)) * WW + (j0 + c)] =
            v + LAMV * (cN * gN + cS * gS + cE * gE + cWd * gW);
    }
}

extern "C" void kernel_launch(void* const* d_in, const int* in_sizes, int n_in,
                              void* d_out, int out_size, void* d_ws, size_t ws_size,
                              hipStream_t stream) {
    (void)in_sizes; (void)n_in; (void)out_size;
    const float* x   = (const float*)d_in[0];
    const float* gw1 = (const float*)d_in[1];
    const float* gb1 = (const float*)d_in[2];
    const float* bng = (const float*)d_in[3];
    const float* bnb = (const float*)d_in[4];
    const float* bnm = (const float*)d_in[5];
    const float* bnv = (const float*)d_in[6];
    const float* gw2 = (const float*)d_in[7];
    const float* gb2 = (const float*)d_in[8];
    const float* cw1 = (const float*)d_in[9];
    const float* cb1 = (const float*)d_in[10];
    const float* cw2 = (const float*)d_in[11];
    const float* cb2 = (const float*)d_in[12];
    const float* cw3 = (const float*)d_in[13];
    const float* cb3 = (const float*)d_in[14];
    float* out = (float*)d_out;

    char* base = (char*)d_ws;
    const size_t PX   = (size_t)NB * HH * WW;
    const size_t Z16B = PX * 32 * 2;   // 128 MiB
    const size_t GUB  = PX * 8 * 4;    //  64 MiB
    const size_t XB   = PX * 4;        //   8 MiB

    const int zmode = (ws_size >= Z16B + GUB + XB + WPKTOT) ? 1 : 0;

    unsigned short* Zh = nullptr;
    float *guidp, *bufA; unsigned short* wpk;
    if (zmode == 1) {
        Zh    = (unsigned short*)base;
        guidp = (float*)(base + Z16B);
        bufA  = (float*)(base + Z16B + GUB);
        wpk   = (unsigned short*)(base + Z16B + GUB + XB);
    } else {
        guidp = (float*)base;
        bufA  = (float*)(base + GUB);
        wpk   = (unsigned short*)(base + GUB + XB);
    }

    dim3 grid(WW / TT, HH / TT, NB);
    prep_kernel<<<1, 256, 0, stream>>>(cw1, cw2, cw3, wpk);
    guidance_kernel<<<grid, BSG, 0, stream>>>(x, gw1, gb1, bng, bnb, bnm, bnv, gw2, gb2, guidp);
    if (zmode)
        z_kernel<<<grid, 256, 0, stream>>>(guidp, cw1, cb1, Zh);

    const float* cur = x;
    for (int it = 0; it < 10; ++it) {
        float* dst = (it & 1) ? out : bufA;   // it9 (odd) lands in d_out
        if (zmode == 1)
            iter_kernel<1><<<grid, BSI, 0, stream>>>(cur, dst, Zh, guidp, wpk, cb1, cb2, cb3);
        else
            iter_kernel<0><<<grid, BSI, 0, stream>>>(cur, dst, Zh, guidp, wpk, cb1, cb2, cb3);
        cur = dst;
    }
}

// Round 8
// 1724.476 us; speedup vs baseline: 222.9055x; 2.3504x over previous
//
#include <hip/hip_runtime.h>
#include <hip/hip_bf16.h>

#define HH 512
#define WW 512
#define NB 8
#define TT 16
#define BSG 384
#define BSI 256
#define EPSV 1e-5f
#define LAMV 0.1f

typedef __attribute__((ext_vector_type(4))) float f32x4;
typedef __attribute__((ext_vector_type(4))) short s16x4;
typedef __attribute__((ext_vector_type(8))) short s16x8;

#define MFMA16 __builtin_amdgcn_mfma_f32_16x16x32_bf16

// packed-weight blob offsets (bytes)
#define W2PK 0        // [9 tap][16 co][32 ch] bf16            (9216 B)
#define W3PK 9216     // [5 row][160 k] bf16                   (1600 B)
#define W1PKG 10816   // [32 co][64 k]  k=tap*4+gradch         (4096 B)
#define W1PKU 14912   // [32 co][96 k]  k=tap*8+guidch         (6144 B)
#define WPKTOT 21056

__device__ __forceinline__ float sigmoidf_(float v) { return 1.0f / (1.0f + __expf(-v)); }

__device__ __forceinline__ short f2bf(float f) {
    __hip_bfloat16 h = __float2bfloat16(f);
    short s; __builtin_memcpy(&s, &h, 2); return s;
}
__device__ __forceinline__ unsigned pack2bf(float a, float b) {
    __hip_bfloat16 ha = __float2bfloat16(a), hb = __float2bfloat16(b);
    unsigned short ua, ub;
    __builtin_memcpy(&ua, &ha, 2); __builtin_memcpy(&ub, &hb, 2);
    return (unsigned)ua | ((unsigned)ub << 16);
}

// ---------------------------------------------------------------------------
// prep: pack conv weights into fragment-major bf16 blobs (runs once, 1 block)
// ---------------------------------------------------------------------------
__global__ __launch_bounds__(256) void prep_kernel(
    const float* __restrict__ cw1, const float* __restrict__ cw2,
    const float* __restrict__ cw3, unsigned short* __restrict__ wpk)
{
    const int tid = threadIdx.x;
    // W2PK [t][co][ch]
    for (int e = tid; e < 4608; e += 256) {
        int ch = e & 31, co = (e >> 5) & 15, t = e >> 9;
        wpk[W2PK / 2 + e] = (unsigned short)f2bf(cw2[(co * 32 + ch) * 9 + t]);
    }
    // W3PK [row][k], k=tap*16+ci ; row 4 and k>=144 zero
    for (int e = tid; e < 800; e += 256) {
        int k = e % 160, row = e / 160;
        float v = 0.f;
        if (row < 4 && k < 144) { int tp = k / 16, ci = k & 15; v = cw3[(row * 16 + ci) * 9 + tp]; }
        wpk[W3PK / 2 + e] = (unsigned short)f2bf(v);
    }
    // W1PKG [co][k], k=tap*4+gradch (ch 0..3), k>=36 zero
    for (int e = tid; e < 2048; e += 256) {
        int k = e & 63, co = e >> 6;
        float v = 0.f;
        if (k < 36) { int tp = k >> 2, ch = k & 3; v = cw1[(co * 12 + ch) * 9 + tp]; }
        wpk[W1PKG / 2 + e] = (unsigned short)f2bf(v);
    }
    // W1PKU [co][k], k=tap*8+guidch (ch 0..7 -> input ch 4+ch), k>=72 zero
    for (int e = tid; e < 3072; e += 256) {
        int k = e % 96, co = e / 96;
        float v = 0.f;
        if (k < 72) { int tp = k >> 3, ch = k & 7; v = cw1[(co * 12 + 4 + ch) * 9 + tp]; }
        wpk[W1PKU / 2 + e] = (unsigned short)f2bf(v);
    }
}

// ---------------------------------------------------------------------------
// Guidance: avgpool3 -> dilated conv(1->16)+BN+relu -> conv(16->8)+sigmoid.
// Output: bf16 PIXEL-MAJOR [b][i][j][8] (16 B per pixel, one uint4 store).
// ---------------------------------------------------------------------------
__global__ __launch_bounds__(BSG) void guidance_kernel(
    const float* __restrict__ x, const float* __restrict__ gw1, const float* __restrict__ gb1,
    const float* __restrict__ bng, const float* __restrict__ bnb, const float* __restrict__ bnm,
    const float* __restrict__ bnv, const float* __restrict__ gw2, const float* __restrict__ gb2,
    unsigned short* __restrict__ guid16)
{
    __shared__ __align__(16) float s_wg1[9][16];
    __shared__ __align__(16) float s_wg2[16][9][8];
    __shared__ float s_inv[16], s_off[16], s_b1[16], s_b2[8];
    __shared__ float s_x[24][25];
    __shared__ float s_xs[22][23];
    __shared__ float s_g[16][18][19];

    const int tid = threadIdx.x;
    const int b  = blockIdx.z;
    const int i0 = blockIdx.y * TT, j0 = blockIdx.x * TT;
    const int o = i0 - 4, p = j0 - 4;
    const float* xb = x + (size_t)b * HH * WW;

    for (int e = tid; e < 144; e += BSG) { int co = e % 16, t = e / 16; s_wg1[t][co] = gw1[co * 9 + t]; }
    for (int e = tid; e < 1152; e += BSG) {
        int co = e % 8, t = (e / 8) % 9, ci = e / 72;
        s_wg2[ci][t][co] = gw2[(co * 16 + ci) * 9 + t];
    }
    if (tid < 16) {
        float iv = bng[tid] * rsqrtf(bnv[tid] + EPSV);
        s_inv[tid] = iv; s_off[tid] = bnb[tid] - bnm[tid] * iv; s_b1[tid] = gb1[tid];
    }
    if (tid < 8) s_b2[tid] = gb2[tid];

    for (int e = tid; e < 576; e += BSG) {
        int r = e / 24, c = e % 24;
        int gi = o + r, gj = p + c;
        float v = 0.f;
        if (gi >= 0 && gi < HH && gj >= 0 && gj < WW) v = xb[gi * WW + gj];
        s_x[r][c] = v;
    }
    __syncthreads();

    for (int e = tid; e < 484; e += BSG) {
        int a = e / 22, bb = e % 22;
        int gi = o + a + 1, gj = p + bb + 1;
        float v = 0.f;
        if (gi >= 0 && gi < HH && gj >= 0 && gj < WW) {
            float s = 0.f;
            #pragma unroll
            for (int dr = 0; dr < 3; ++dr)
                #pragma unroll
                for (int dc = 0; dc < 3; ++dc) s += s_x[a + dr][bb + dc];
            v = s * (1.0f / 9.0f);
        }
        s_xs[a][bb] = v;
    }
    __syncthreads();

    for (int e = tid; e < 324; e += BSG) {
        int a = e / 18, bb = e % 18;
        int gi = o + a + 3, gj = p + bb + 3;
        bool in = (gi >= 0 && gi < HH && gj >= 0 && gj < WW);
        float acc[16];
        #pragma unroll
        for (int k = 0; k < 16; ++k) acc[k] = s_b1[k];
        #pragma unroll
        for (int kh = 0; kh < 3; ++kh)
            #pragma unroll
            for (int kw = 0; kw < 3; ++kw) {
                float av = s_xs[a + 2 * kh][bb + 2 * kw];
                #pragma unroll
                for (int q4 = 0; q4 < 4; ++q4) {
                    const float4 w = *(const float4*)&s_wg1[kh * 3 + kw][q4 * 4];
                    acc[q4*4+0] = fmaf(w.x, av, acc[q4*4+0]);
                    acc[q4*4+1] = fmaf(w.y, av, acc[q4*4+1]);
                    acc[q4*4+2] = fmaf(w.z, av, acc[q4*4+2]);
                    acc[q4*4+3] = fmaf(w.w, av, acc[q4*4+3]);
                }
            }
        #pragma unroll
        for (int k = 0; k < 16; ++k) {
            float val = acc[k] * s_inv[k] + s_off[k];
            s_g[k][a][bb] = in ? fmaxf(val, 0.f) : 0.f;
        }
    }
    __syncthreads();

    if (tid < 256) {
        int a = tid / 16, bb = tid % 16;
        int gi = i0 + a, gj = j0 + bb;
        float acc[8];
        #pragma unroll
        for (int k = 0; k < 8; ++k) acc[k] = s_b2[k];
        for (int ci = 0; ci < 16; ++ci)
            #pragma unroll
            for (int t9 = 0; t9 < 9; ++t9) {
                float av = s_g[ci][a + t9 / 3][bb + t9 % 3];
                #pragma unroll
                for (int q4 = 0; q4 < 2; ++q4) {
                    const float4 w = *(const float4*)&s_wg2[ci][t9][q4 * 4];
                    acc[q4*4+0] = fmaf(w.x, av, acc[q4*4+0]);
                    acc[q4*4+1] = fmaf(w.y, av, acc[q4*4+1]);
                    acc[q4*4+2] = fmaf(w.z, av, acc[q4*4+2]);
                    acc[q4*4+3] = fmaf(w.w, av, acc[q4*4+3]);
                }
            }
        uint4 u;
        u.x = pack2bf(sigmoidf_(acc[0]), sigmoidf_(acc[1]));
        u.y = pack2bf(sigmoidf_(acc[2]), sigmoidf_(acc[3]));
        u.z = pack2bf(sigmoidf_(acc[4]), sigmoidf_(acc[5]));
        u.w = pack2bf(sigmoidf_(acc[6]), sigmoidf_(acc[7]));
        *(uint4*)&guid16[(((size_t)b * HH + gi) * WW + gj) * 8] = u;
    }
}

// ---------------------------------------------------------------------------
// Fused diffusion iteration, MFMA bf16 16x16x32, no Z intermediate.
// conv1 = 2 MFMA (grads, K=64 pad of 36) + 3 MFMA (guid, K=96 pad of 72).
// guid read as pixel-major bf16 uint4 (L3-resident, dense lines).
// LDS: s_x 2304 | ACTG [22][22][4] 3872 | ACTU [22][22][8] 7744 |
//      C1 4x[20][21s][8] 26880 | C2 2x[18][19s][8] 10944 | C3 alias C1.
// TOT 51744 -> 3 blocks/CU.
// ---------------------------------------------------------------------------
__global__ __launch_bounds__(BSI) void iter_kernel(
    const float* __restrict__ xin, float* __restrict__ xout,
    const unsigned short* __restrict__ guid16,
    const unsigned short* __restrict__ wpk, const float* __restrict__ cb1,
    const float* __restrict__ cb2, const float* __restrict__ cb3)
{
    constexpr int ACTG = 2304;
    constexpr int ACTU = 6176;
    constexpr int C1   = 13920;
    constexpr int C2   = 40800;
    constexpr int C3   = C1;           // aliases dead C1 after B4
    constexpr int TOT  = 51744;
    constexpr int C1P  = 6720;         // c1 plane stride (20*21*8*2)
    constexpr int C2P  = 5472;         // c2 plane stride (18*19*8*2)

    __shared__ __align__(16) char S[TOT];
    float* s_x = (float*)S;

    const int tid = threadIdx.x;
    const int bz = blockIdx.z;
    const int i0 = blockIdx.y * TT, j0 = blockIdx.x * TT;
    const int o = i0 - 4, p = j0 - 4;
    const float* xb = xin + (size_t)bz * HH * WW;

    // ---- stage x tile (clamped: edge-pad semantics) ----
    for (int e = tid; e < 576; e += BSI) {
        int r = e / 24, c = e % 24;
        int gi = min(max(o + r, 0), HH - 1);
        int gj = min(max(p + c, 0), WW - 1);
        s_x[e] = xb[gi * WW + gj];
    }

    const int lane = tid & 63;
    const int g = lane >> 4;
    const int col = lane & 15;
    const int wv = tid >> 6;

    // per-lane biases
    const float bias2_v = cb2[col];
    const float bias3_v = (col < 4) ? cb3[col] : 0.f;
    const float b1v0 = cb1[col];
    const float b1v1 = cb1[col + 16];

    // B-fragments from packed global blob (L1/L2-hot, coalesced)
    s16x8 fw2[9], fw3[5], fwg[4], fwu[6];
    #pragma unroll
    for (int t = 0; t < 9; ++t)
        fw2[t] = *(const s16x8*)&wpk[W2PK / 2 + (t * 16 + col) * 32 + g * 8];
    {
        int w3r = col < 4 ? col : 4;
        #pragma unroll
        for (int q = 0; q < 5; ++q)
            fw3[q] = *(const s16x8*)&wpk[W3PK / 2 + w3r * 160 + q * 32 + g * 8];
    }
    #pragma unroll
    for (int h = 0; h < 2; ++h) {
        #pragma unroll
        for (int mf = 0; mf < 2; ++mf)
            fwg[h * 2 + mf] = *(const s16x8*)&wpk[W1PKG / 2 + (col + 16 * h) * 64 + mf * 32 + g * 8];
        #pragma unroll
        for (int q = 0; q < 3; ++q)
            fwu[h * 3 + q] = *(const s16x8*)&wpk[W1PKU / 2 + (col + 16 * h) * 96 + q * 32 + g * 8];
    }
    __syncthreads();   // B1: s_x staged

    // ---- gradients + guid staging, rel [1,23) ----
    for (int e = tid; e < 484; e += BSI) {
        int r = e / 22, c = e % 22;
        int gi = o + 1 + r, gj = p + 1 + c;
        bool in = ((unsigned)gi < (unsigned)HH) && ((unsigned)gj < (unsigned)WW);
        float v  = s_x[(r + 1) * 24 + c + 1];
        float gN = s_x[(r + 0) * 24 + c + 1] - v;
        float gS = s_x[(r + 2) * 24 + c + 1] - v;
        float gE = s_x[(r + 1) * 24 + c + 2] - v;
        float gW = s_x[(r + 1) * 24 + c + 0] - v;
        if (!in) { gN = gS = gE = gW = 0.f; }
        *(uint2*)&S[ACTG + (r * 22 + c) * 8] = make_uint2(pack2bf(gN, gS), pack2bf(gE, gW));
        uint4 gu = make_uint4(0u, 0u, 0u, 0u);
        if (in) gu = *(const uint4*)&guid16[(((size_t)bz * HH + gi) * WW + gj) * 8];
        *(uint4*)&S[ACTU + (r * 22 + c) * 16] = gu;
    }
    __syncthreads();   // B2: activations ready

    // ---- conv1 -> c1 planes (30 M-tiles: 10 bands x cols {0,8,12}) ----
    {
        const int t0 = 2 * g, t1 = t0 + 1;
        const int dr0 = t0 / 3, dc0 = t0 % 3, dr1 = t1 / 3, dc1 = t1 % 3;
        for (int t = wv; t < 30; t += 4) {
            int band = t / 3, m3 = t % 3;
            int tc = m3 * 8 - (m3 >> 1) * 4;          // {0,8,12}
            int prA = band * 2 + (col >> 3), pcA = tc + (col & 7);
            // grad A-frags (k=tap*4+gc)
            s16x4 a0 = *(const s16x4*)&S[ACTG + ((prA + dr0) * 22 + (pcA + dc0)) * 8];
            s16x4 a1 = *(const s16x4*)&S[ACTG + ((prA + dr1) * 22 + (pcA + dc1)) * 8];
            s16x4 a2 = *(const s16x4*)&S[ACTG + ((prA + 2) * 22 + (pcA + 2)) * 8];   // tap8
            s16x8 A1 = __builtin_shufflevector(a0, a1, 0, 1, 2, 3, 4, 5, 6, 7);
            s16x8 A2 = __builtin_shufflevector(a2, a2, 0, 1, 2, 3, 0, 1, 2, 3);
            // guid A-frags (k=tap*8+ch): tap = q*4+g, zero when tap>8
            s16x8 Au[3];
            #pragma unroll
            for (int q = 0; q < 3; ++q) {
                int tg = q * 4 + g;
                int dtr = tg / 3, dtc = tg % 3;
                if (tg <= 8)
                    Au[q] = *(const s16x8*)&S[ACTU + ((prA + dtr) * 22 + (pcA + dtc)) * 16];
                else
                    Au[q] = (s16x8){0, 0, 0, 0, 0, 0, 0, 0};
            }
            int prD = band * 2 + (g >> 1);
            int pc0 = tc + ((4 * g) & 7);
            int giD = o + 2 + prD;
            bool rin = (unsigned)giD < (unsigned)HH;
            #pragma unroll
            for (int h = 0; h < 2; ++h) {
                int co = col + 16 * h;
                float bi = h ? b1v1 : b1v0;
                f32x4 acc = {bi, bi, bi, bi};
                acc = MFMA16(A1, fwg[h * 2 + 0], acc, 0, 0, 0);
                acc = MFMA16(A2, fwg[h * 2 + 1], acc, 0, 0, 0);
                acc = MFMA16(Au[0], fwu[h * 3 + 0], acc, 0, 0, 0);
                acc = MFMA16(Au[1], fwu[h * 3 + 1], acc, 0, 0, 0);
                acc = MFMA16(Au[2], fwu[h * 3 + 2], acc, 0, 0, 0);
                #pragma unroll
                for (int i = 0; i < 4; ++i) {
                    int pcD = pc0 + i;
                    bool in = rin && ((unsigned)(p + 2 + pcD) < (unsigned)WW);
                    float v = in ? fmaxf(acc[i], 0.f) : 0.f;
                    *(short*)&S[C1 + (co >> 3) * C1P + (prD * 21 + pcD) * 16 + (co & 7) * 2] = f2bf(v);
                }
            }
        }
    }
    __syncthreads();   // B3: c1 ready

    // ---- conv2 -> c2 planes (27 M-tiles: 9 bands x cols {0,8,10}) ----
    for (int t = wv; t < 27; t += 4) {
        int band = t / 3, m3 = t % 3;
        int tc = m3 * 8 - (m3 >> 1) * 6;              // {0,8,10}
        int prA = band * 2 + (col >> 3), pcA = tc + (col & 7);
        f32x4 acc = {0.f, 0.f, 0.f, 0.f};
        #pragma unroll
        for (int tp = 0; tp < 9; ++tp) {
            int dr = tp / 3, dc = tp % 3;
            s16x8 Af = *(const s16x8*)&S[C1 + g * C1P + ((prA + dr) * 21 + (pcA + dc)) * 16];
            acc = MFMA16(Af, fw2[tp], acc, 0, 0, 0);
        }
        int prD = band * 2 + (g >> 1);
        int pc0 = tc + ((4 * g) & 7);
        bool rin = (unsigned)(o + 3 + prD) < (unsigned)HH;
        #pragma unroll
        for (int i = 0; i < 4; ++i) {
            int pcD = pc0 + i;
            bool in = rin && ((unsigned)(p + 3 + pcD) < (unsigned)WW);
            float v = in ? fmaxf(acc[i] + bias2_v, 0.f) : 0.f;
            *(short*)&S[C2 + (col >> 3) * C2P + (prD * 19 + pcD) * 16 + (col & 7) * 2] = f2bf(v);
        }
    }
    __syncthreads();   // B4: c2 ready, c1 dead (C3 may overwrite)

    // ---- conv3 -> c3 (16 M-tiles; K=144->160, 5 mfma) ----
    for (int t = wv; t < 16; t += 4) {
        int band = t >> 1, tc = (t & 1) * 8;
        int rA = band * 2 + (col >> 3), cA = tc + (col & 7);
        f32x4 acc = {0.f, 0.f, 0.f, 0.f};
        #pragma unroll
        for (int q = 0; q < 5; ++q) {
            int tp = 2 * q + (g >> 1); if (tp > 8) tp = 8;
            int dr = tp / 3, dc = tp % 3;
            int half = g & 1;
            s16x8 Af = *(const s16x8*)&S[C2 + half * C2P + ((rA + dr) * 19 + (cA + dc)) * 16];
            acc = MFMA16(Af, fw3[q], acc, 0, 0, 0);
        }
        if (col < 4) {
            int rD = band * 2 + (g >> 1), c0 = tc + ((4 * g) & 7);
            #pragma unroll
            for (int i = 0; i < 4; ++i)
                *(float*)&S[C3 + ((rD * 16 + c0 + i) * 4 + col) * 4] = acc[i] + bias3_v;
        }
    }
    __syncthreads();   // B5: c3 ready

    // ---- sigmoid + diffusion update (f32) ----
    {
        int r = tid >> 4, c = tid & 15;
        f32x4 cc = *(const f32x4*)&S[C3 + tid * 16];
        float cN = sigmoidf_(cc[0]), cS = sigmoidf_(cc[1]);
        float cE = sigmoidf_(cc[2]), cWd = sigmoidf_(cc[3]);
        float v  = s_x[(r + 4) * 24 + c + 4];
        float gN = s_x[(r + 3) * 24 + c + 4] - v;
        float gS = s_x[(r + 5) * 24 + c + 4] - v;
        float gE = s_x[(r + 4) * 24 + c + 5] - v;
        float gW = s_x[(r + 4) * 24 + c + 3] - v;
        xout[((size_t)bz * HH + (i0 + r)) * WW + (j0 + c)] =
            v + LAMV * (cN * gN + cS * gS + cE * gE + cWd * gW);
    }
}

extern "C" void kernel_launch(void* const* d_in, const int* in_sizes, int n_in,
                              void* d_out, int out_size, void* d_ws, size_t ws_size,
                              hipStream_t stream) {
    (void)in_sizes; (void)n_in; (void)out_size; (void)ws_size;
    const float* x   = (const float*)d_in[0];
    const float* gw1 = (const float*)d_in[1];
    const float* gb1 = (const float*)d_in[2];
    const float* bng = (const float*)d_in[3];
    const float* bnb = (const float*)d_in[4];
    const float* bnm = (const float*)d_in[5];
    const float* bnv = (const float*)d_in[6];
    const float* gw2 = (const float*)d_in[7];
    const float* gb2 = (const float*)d_in[8];
    const float* cw1 = (const float*)d_in[9];
    const float* cb1 = (const float*)d_in[10];
    const float* cw2 = (const float*)d_in[11];
    const float* cb2 = (const float*)d_in[12];
    const float* cw3 = (const float*)d_in[13];
    const float* cb3 = (const float*)d_in[14];
    float* out = (float*)d_out;

    char* base = (char*)d_ws;
    const size_t PX    = (size_t)NB * HH * WW;
    const size_t GU16B = PX * 8 * 2;   // 32 MiB guid bf16 pixel-major
    const size_t XB    = PX * 4;       //  8 MiB

    unsigned short* guid16 = (unsigned short*)base;
    float* bufA            = (float*)(base + GU16B);
    unsigned short* wpk    = (unsigned short*)(base + GU16B + XB);

    dim3 grid(WW / TT, HH / TT, NB);
    prep_kernel<<<1, 256, 0, stream>>>(cw1, cw2, cw3, wpk);
    guidance_kernel<<<grid, BSG, 0, stream>>>(x, gw1, gb1, bng, bnb, bnm, bnv, gw2, gb2, guid16);

    const float* cur = x;
    for (int it = 0; it < 10; ++it) {
        float* dst = (it & 1) ? out : bufA;   // it9 (odd) lands in d_out
        iter_kernel<<<grid, BSI, 0, stream>>>(cur, dst, guid16, wpk, cb1, cb2, cb3);
        cur = dst;
    }
}

// Round 9
// 1510.472 us; speedup vs baseline: 254.4868x; 1.1417x over previous
//
#include <hip/hip_runtime.h>
#include <hip/hip_bf16.h>

#define HH 512
#define WW 512
#define NB 8
#define TT 16
#define BSI 256
#define EPSV 1e-5f
#define LAMV 0.1f

typedef __attribute__((ext_vector_type(4))) float f32x4;
typedef __attribute__((ext_vector_type(4))) short s16x4;
typedef __attribute__((ext_vector_type(8))) short s16x8;

#define MFMA16 __builtin_amdgcn_mfma_f32_16x16x32_bf16

// packed-weight blob offsets (bytes)
#define W2PK 0        // [9 tap][16 co][32 ch] bf16            (9216 B)
#define W3PK 9216     // [5 row][160 k] bf16                   (1600 B)
#define W1PKG 10816   // [32 co][64 k]  k=tap*4+gradch         (4096 B)
#define W1PKU 14912   // [32 co][96 k]  k=tap*8+guidch         (6144 B)
#define W4PK  21056   // [16 col][160 k] gw2, k=tap*16+ci      (5120 B)
#define WPKTOT 26176

__device__ __forceinline__ float sigmoidf_(float v) { return 1.0f / (1.0f + __expf(-v)); }

__device__ __forceinline__ short f2bf(float f) {
    __hip_bfloat16 h = __float2bfloat16(f);
    short s; __builtin_memcpy(&s, &h, 2); return s;
}
__device__ __forceinline__ unsigned pack2bf(float a, float b) {
    __hip_bfloat16 ha = __float2bfloat16(a), hb = __float2bfloat16(b);
    unsigned short ua, ub;
    __builtin_memcpy(&ua, &ha, 2); __builtin_memcpy(&ub, &hb, 2);
    return (unsigned)ua | ((unsigned)ub << 16);
}

// ---------------------------------------------------------------------------
// prep: pack conv weights into fragment-major bf16 blobs (runs once, 1 block)
// ---------------------------------------------------------------------------
__global__ __launch_bounds__(256) void prep_kernel(
    const float* __restrict__ cw1, const float* __restrict__ cw2,
    const float* __restrict__ cw3, const float* __restrict__ gw2,
    unsigned short* __restrict__ wpk)
{
    const int tid = threadIdx.x;
    // W2PK [t][co][ch]
    for (int e = tid; e < 4608; e += 256) {
        int ch = e & 31, co = (e >> 5) & 15, t = e >> 9;
        wpk[W2PK / 2 + e] = (unsigned short)f2bf(cw2[(co * 32 + ch) * 9 + t]);
    }
    // W3PK [row][k], k=tap*16+ci ; row 4 and k>=144 zero
    for (int e = tid; e < 800; e += 256) {
        int k = e % 160, row = e / 160;
        float v = 0.f;
        if (row < 4 && k < 144) { int tp = k / 16, ci = k & 15; v = cw3[(row * 16 + ci) * 9 + tp]; }
        wpk[W3PK / 2 + e] = (unsigned short)f2bf(v);
    }
    // W1PKG [co][k], k=tap*4+gradch (ch 0..3), k>=36 zero
    for (int e = tid; e < 2048; e += 256) {
        int k = e & 63, co = e >> 6;
        float v = 0.f;
        if (k < 36) { int tp = k >> 2, ch = k & 3; v = cw1[(co * 12 + ch) * 9 + tp]; }
        wpk[W1PKG / 2 + e] = (unsigned short)f2bf(v);
    }
    // W1PKU [co][k], k=tap*8+guidch (ch 0..7 -> input ch 4+ch), k>=72 zero
    for (int e = tid; e < 3072; e += 256) {
        int k = e % 96, co = e / 96;
        float v = 0.f;
        if (k < 72) { int tp = k >> 3, ch = k & 7; v = cw1[(co * 12 + 4 + ch) * 9 + tp]; }
        wpk[W1PKU / 2 + e] = (unsigned short)f2bf(v);
    }
    // W4PK [col][k], k=tap*16+ci ; col>=8 and k>=144 zero
    for (int e = tid; e < 2560; e += 256) {
        int k = e % 160, col = e / 160;
        float v = 0.f;
        if (col < 8 && k < 144) { int tp = k / 16, ci = k & 15; v = gw2[(col * 16 + ci) * 9 + tp]; }
        wpk[W4PK / 2 + e] = (unsigned short)f2bf(v);
    }
}

// ---------------------------------------------------------------------------
// Guidance: avgpool3 -> dilated conv(1->16)+BN+relu (VALU) -> conv(16->8,
// MFMA K=160)+sigmoid. Output bf16 pixel-major [b][i][j][8].
// LDS: WG1 [9][16]f32 @0 | BN @576 | SX 28x28 f32 @768 | SXS 26x26 f32 @3904
//      | SG 2x[18][18cells][8ch]bf16 @6608 | SR [256][8]bf16 @768 (alias SX)
// ---------------------------------------------------------------------------
__global__ __launch_bounds__(256) void guidance_kernel(
    const float* __restrict__ x, const float* __restrict__ gw1, const float* __restrict__ gb1,
    const float* __restrict__ bng, const float* __restrict__ bnb, const float* __restrict__ bnm,
    const float* __restrict__ bnv, const float* __restrict__ gb2,
    const unsigned short* __restrict__ wpk, unsigned short* __restrict__ guid16)
{
    constexpr int WG1 = 0, BNO = 576, SX = 768, SXS = 3904, SG = 6608, SR = 768;
    constexpr int GP = 18 * 18 * 16;   // 5184
    __shared__ __align__(16) char S[16976];

    const int tid = threadIdx.x;
    const int b  = blockIdx.z;
    const int i0 = blockIdx.y * TT, j0 = blockIdx.x * TT;
    const float* xb = x + (size_t)b * HH * WW;

    const int lane = tid & 63;
    const int g = lane >> 4;
    const int col = lane & 15;
    const int wv = tid >> 6;

    // stage weights + BN constants
    for (int e = tid; e < 144; e += 256) {
        int co = e % 16, t = e / 16;
        ((float*)&S[WG1])[t * 16 + co] = gw1[co * 9 + t];
    }
    if (tid < 16) {
        float iv = bng[tid] * rsqrtf(bnv[tid] + EPSV);
        ((float*)&S[BNO])[tid]      = iv;
        ((float*)&S[BNO + 64])[tid] = bnb[tid] - bnm[tid] * iv;
        ((float*)&S[BNO + 128])[tid] = gb1[tid];
    }
    // g2 B-fragments (global, L2-hot)
    s16x8 fw4[5];
    #pragma unroll
    for (int q = 0; q < 5; ++q)
        fw4[q] = *(const s16x8*)&wpk[W4PK / 2 + col * 160 + q * 32 + g * 8];
    const float b2v = (col < 8) ? gb2[col] : 0.f;

    // stage x [i0-6, i0+22) x [j0-6, j0+22), zero off-image
    for (int e = tid; e < 784; e += 256) {
        int u = e / 28, v = e % 28;
        int gi = i0 - 6 + u, gj = j0 - 6 + v;
        float val = 0.f;
        if ((unsigned)gi < (unsigned)HH && (unsigned)gj < (unsigned)WW) val = xb[gi * WW + gj];
        ((float*)&S[SX])[e] = val;
    }
    __syncthreads();   // B1

    // xs = avgpool3 on [i0-5, i0+21), zero off-image
    for (int e = tid; e < 676; e += 256) {
        int u = e / 26, v = e % 26;
        int gi = i0 - 5 + u, gj = j0 - 5 + v;
        float val = 0.f;
        if ((unsigned)gi < (unsigned)HH && (unsigned)gj < (unsigned)WW) {
            float s = 0.f;
            #pragma unroll
            for (int du = 0; du < 3; ++du)
                #pragma unroll
                for (int dv = 0; dv < 3; ++dv)
                    s += ((float*)&S[SX])[(u + du) * 28 + (v + dv)];
            val = s * (1.0f / 9.0f);
        }
        ((float*)&S[SXS])[e] = val;
    }
    __syncthreads();   // B2

    // g1: dilated conv(1->16)+BN+relu on [i0-1, i0+17), bf16 planes
    for (int e = tid; e < 324; e += 256) {
        int r = e / 18, c = e % 18;
        int gi = i0 - 1 + r, gj = j0 - 1 + c;
        bool in = (unsigned)gi < (unsigned)HH && (unsigned)gj < (unsigned)WW;
        float acc[16];
        #pragma unroll
        for (int k = 0; k < 16; ++k) acc[k] = ((float*)&S[BNO + 128])[k];
        #pragma unroll
        for (int kh = 0; kh < 3; ++kh)
            #pragma unroll
            for (int kw = 0; kw < 3; ++kw) {
                float av = ((float*)&S[SXS])[(r + 2 * kh + 2) * 26 + (c + 2 * kw + 2)];
                #pragma unroll
                for (int q4 = 0; q4 < 4; ++q4) {
                    const float4 w = *(const float4*)&((float*)&S[WG1])[(kh * 3 + kw) * 16 + q4 * 4];
                    acc[q4*4+0] = fmaf(w.x, av, acc[q4*4+0]);
                    acc[q4*4+1] = fmaf(w.y, av, acc[q4*4+1]);
                    acc[q4*4+2] = fmaf(w.z, av, acc[q4*4+2]);
                    acc[q4*4+3] = fmaf(w.w, av, acc[q4*4+3]);
                }
            }
        float gval[16];
        #pragma unroll
        for (int k = 0; k < 16; ++k) {
            float v = acc[k] * ((float*)&S[BNO])[k] + ((float*)&S[BNO + 64])[k];
            gval[k] = in ? fmaxf(v, 0.f) : 0.f;
        }
        uint4 h0, h1;
        h0.x = pack2bf(gval[0], gval[1]);  h0.y = pack2bf(gval[2], gval[3]);
        h0.z = pack2bf(gval[4], gval[5]);  h0.w = pack2bf(gval[6], gval[7]);
        h1.x = pack2bf(gval[8], gval[9]);  h1.y = pack2bf(gval[10], gval[11]);
        h1.z = pack2bf(gval[12], gval[13]); h1.w = pack2bf(gval[14], gval[15]);
        *(uint4*)&S[SG + (r * 18 + c) * 16]      = h0;
        *(uint4*)&S[SG + GP + (r * 18 + c) * 16] = h1;
    }
    __syncthreads();   // B3

    // g2: conv(16->8) via MFMA, 16 M-tiles, sigmoid, stage to SR
    for (int t = wv; t < 16; t += 4) {
        int band = t >> 1, tc = (t & 1) * 8;
        int rA = band * 2 + (col >> 3), cA = tc + (col & 7);
        f32x4 acc = {0.f, 0.f, 0.f, 0.f};
        #pragma unroll
        for (int q = 0; q < 5; ++q) {
            int tp = 2 * q + (g >> 1); if (tp > 8) tp = 8;
            int dr = tp / 3, dc = tp % 3;
            s16x8 Af = *(const s16x8*)&S[SG + (g & 1) * GP + ((rA + dr) * 18 + (cA + dc)) * 16];
            acc = MFMA16(Af, fw4[q], acc, 0, 0, 0);
        }
        if (col < 8) {
            int rD = band * 2 + (g >> 1), c0 = tc + ((4 * g) & 7);
            #pragma unroll
            for (int i = 0; i < 4; ++i) {
                float s = sigmoidf_(acc[i] + b2v);
                *(short*)&S[SR + ((rD * 16 + c0 + i) * 8 + col) * 2] = f2bf(s);
            }
        }
    }
    __syncthreads();   // B4

    // store guid16 pixel-major
    {
        uint4 u = *(const uint4*)&S[SR + tid * 16];
        int gi = i0 + (tid >> 4), gj = j0 + (tid & 15);
        *(uint4*)&guid16[(((size_t)b * HH + gi) * WW + gj) * 8] = u;
    }
}

// ---------------------------------------------------------------------------
// Fused diffusion iteration, MFMA bf16 16x16x32, no Z intermediate.
// guid staged in phase 0 (no s_x dependency -> latency overlap).
// LDS: s_x 2304 | ACTG [22][22][4] 3872 | ACTU [22][22][8] 7744 |
//      C1 4x[20][20][8] 25600 | C2 2x[18][18][8] 10368 | C3 alias C1.
// TOT 49888 -> 3 blocks/CU. XCD swizzle: one batch-image per XCD.
// ---------------------------------------------------------------------------
__global__ __launch_bounds__(BSI) void iter_kernel(
    const float* __restrict__ xin, float* __restrict__ xout,
    const unsigned short* __restrict__ guid16,
    const unsigned short* __restrict__ wpk, const float* __restrict__ cb1,
    const float* __restrict__ cb2, const float* __restrict__ cb3)
{
    constexpr int ACTG = 2304;
    constexpr int ACTU = 6176;
    constexpr int C1   = 13920;
    constexpr int C2   = 39520;
    constexpr int C3   = C1;           // aliases dead C1 after B4
    constexpr int TOT  = 49888;
    constexpr int C1P  = 6400;         // c1 plane stride (20*20*8*2)
    constexpr int C2P  = 5184;         // c2 plane stride (18*18*8*2)

    __shared__ __align__(16) char S[TOT];
    float* s_x = (float*)S;

    const int tid = threadIdx.x;
    // XCD-aware swizzle: 8192 blocks, image bz -> XCD bz
    const int flat = blockIdx.x;
    const int nid  = (flat & 7) * 1024 + (flat >> 3);
    const int bz   = nid >> 10;
    const int i0   = ((nid >> 5) & 31) * TT;
    const int j0   = (nid & 31) * TT;
    const int o = i0 - 4, p = j0 - 4;
    const float* xb = xin + (size_t)bz * HH * WW;

    // ---- phase 0: stage x tile (clamped) + guid (independent of s_x) ----
    for (int e = tid; e < 576; e += BSI) {
        int r = e / 24, c = e % 24;
        int gi = min(max(o + r, 0), HH - 1);
        int gj = min(max(p + c, 0), WW - 1);
        s_x[e] = xb[gi * WW + gj];
    }
    for (int e = tid; e < 484; e += BSI) {
        int r = e / 22, c = e % 22;
        int gi = o + 1 + r, gj = p + 1 + c;
        bool in = ((unsigned)gi < (unsigned)HH) && ((unsigned)gj < (unsigned)WW);
        uint4 gu = make_uint4(0u, 0u, 0u, 0u);
        if (in) gu = *(const uint4*)&guid16[(((size_t)bz * HH + gi) * WW + gj) * 8];
        *(uint4*)&S[ACTU + (r * 22 + c) * 16] = gu;
    }

    const int lane = tid & 63;
    const int g = lane >> 4;
    const int col = lane & 15;
    const int wv = tid >> 6;

    // per-lane biases
    const float bias2_v = cb2[col];
    const float bias3_v = (col < 4) ? cb3[col] : 0.f;
    const float b1v0 = cb1[col];
    const float b1v1 = cb1[col + 16];

    // B-fragments from packed global blob (L1/L2-hot, coalesced)
    s16x8 fw2[9], fw3[5], fwg[4], fwu[6];
    #pragma unroll
    for (int t = 0; t < 9; ++t)
        fw2[t] = *(const s16x8*)&wpk[W2PK / 2 + (t * 16 + col) * 32 + g * 8];
    {
        int w3r = col < 4 ? col : 4;
        #pragma unroll
        for (int q = 0; q < 5; ++q)
            fw3[q] = *(const s16x8*)&wpk[W3PK / 2 + w3r * 160 + q * 32 + g * 8];
    }
    #pragma unroll
    for (int h = 0; h < 2; ++h) {
        #pragma unroll
        for (int mf = 0; mf < 2; ++mf)
            fwg[h * 2 + mf] = *(const s16x8*)&wpk[W1PKG / 2 + (col + 16 * h) * 64 + mf * 32 + g * 8];
        #pragma unroll
        for (int q = 0; q < 3; ++q)
            fwu[h * 3 + q] = *(const s16x8*)&wpk[W1PKU / 2 + (col + 16 * h) * 96 + q * 32 + g * 8];
    }
    __syncthreads();   // B1: s_x + ACTU staged

    // ---- gradients (edge-clamped diffs; 0 off-image), rel [1,23) ----
    for (int e = tid; e < 484; e += BSI) {
        int r = e / 22, c = e % 22;
        int gi = o + 1 + r, gj = p + 1 + c;
        bool in = ((unsigned)gi < (unsigned)HH) && ((unsigned)gj < (unsigned)WW);
        float v  = s_x[(r + 1) * 24 + c + 1];
        float gN = s_x[(r + 0) * 24 + c + 1] - v;
        float gS = s_x[(r + 2) * 24 + c + 1] - v;
        float gE = s_x[(r + 1) * 24 + c + 2] - v;
        float gW = s_x[(r + 1) * 24 + c + 0] - v;
        if (!in) { gN = gS = gE = gW = 0.f; }
        *(uint2*)&S[ACTG + (r * 22 + c) * 8] = make_uint2(pack2bf(gN, gS), pack2bf(gE, gW));
    }
    __syncthreads();   // B2: activations ready

    // ---- conv1 -> c1 planes (30 M-tiles: 10 bands x cols {0,8,12}) ----
    {
        const int t0 = 2 * g, t1 = t0 + 1;
        const int dr0 = t0 / 3, dc0 = t0 % 3, dr1 = t1 / 3, dc1 = t1 % 3;
        for (int t = wv; t < 30; t += 4) {
            int band = t / 3, m3 = t % 3;
            int tc = m3 * 8 - (m3 >> 1) * 4;          // {0,8,12}
            int prA = band * 2 + (col >> 3), pcA = tc + (col & 7);
            s16x4 a0 = *(const s16x4*)&S[ACTG + ((prA + dr0) * 22 + (pcA + dc0)) * 8];
            s16x4 a1 = *(const s16x4*)&S[ACTG + ((prA + dr1) * 22 + (pcA + dc1)) * 8];
            s16x4 a2 = *(const s16x4*)&S[ACTG + ((prA + 2) * 22 + (pcA + 2)) * 8];   // tap8
            s16x8 A1 = __builtin_shufflevector(a0, a1, 0, 1, 2, 3, 4, 5, 6, 7);
            s16x8 A2 = __builtin_shufflevector(a2, a2, 0, 1, 2, 3, 0, 1, 2, 3);
            s16x8 Au[3];
            #pragma unroll
            for (int q = 0; q < 3; ++q) {
                int tg = q * 4 + g;
                int dtr = tg / 3, dtc = tg % 3;
                if (tg <= 8)
                    Au[q] = *(const s16x8*)&S[ACTU + ((prA + dtr) * 22 + (pcA + dtc)) * 16];
                else
                    Au[q] = (s16x8){0, 0, 0, 0, 0, 0, 0, 0};
            }
            int prD = band * 2 + (g >> 1);
            int pc0 = tc + ((4 * g) & 7);
            int giD = o + 2 + prD;
            bool rin = (unsigned)giD < (unsigned)HH;
            #pragma unroll
            for (int h = 0; h < 2; ++h) {
                int co = col + 16 * h;
                float bi = h ? b1v1 : b1v0;
                f32x4 acc = {bi, bi, bi, bi};
                acc = MFMA16(A1, fwg[h * 2 + 0], acc, 0, 0, 0);
                acc = MFMA16(A2, fwg[h * 2 + 1], acc, 0, 0, 0);
                acc = MFMA16(Au[0], fwu[h * 3 + 0], acc, 0, 0, 0);
                acc = MFMA16(Au[1], fwu[h * 3 + 1], acc, 0, 0, 0);
                acc = MFMA16(Au[2], fwu[h * 3 + 2], acc, 0, 0, 0);
                #pragma unroll
                for (int i = 0; i < 4; ++i) {
                    int pcD = pc0 + i;
                    bool in = rin && ((unsigned)(p + 2 + pcD) < (unsigned)WW);
                    float v = in ? fmaxf(acc[i], 0.f) : 0.f;
                    *(short*)&S[C1 + (co >> 3) * C1P + (prD * 20 + pcD) * 16 + (co & 7) * 2] = f2bf(v);
                }
            }
        }
    }
    __syncthreads();   // B3: c1 ready

    // ---- conv2 -> c2 planes (27 M-tiles: 9 bands x cols {0,8,10}) ----
    for (int t = wv; t < 27; t += 4) {
        int band = t / 3, m3 = t % 3;
        int tc = m3 * 8 - (m3 >> 1) * 6;              // {0,8,10}
        int prA = band * 2 + (col >> 3), pcA = tc + (col & 7);
        f32x4 acc = {0.f, 0.f, 0.f, 0.f};
        #pragma unroll
        for (int tp = 0; tp < 9; ++tp) {
            int dr = tp / 3, dc = tp % 3;
            s16x8 Af = *(const s16x8*)&S[C1 + g * C1P + ((prA + dr) * 20 + (pcA + dc)) * 16];
            acc = MFMA16(Af, fw2[tp], acc, 0, 0, 0);
        }
        int prD = band * 2 + (g >> 1);
        int pc0 = tc + ((4 * g) & 7);
        bool rin = (unsigned)(o + 3 + prD) < (unsigned)HH;
        #pragma unroll
        for (int i = 0; i < 4; ++i) {
            int pcD = pc0 + i;
            bool in = rin && ((unsigned)(p + 3 + pcD) < (unsigned)WW);
            float v = in ? fmaxf(acc[i] + bias2_v, 0.f) : 0.f;
            *(short*)&S[C2 + (col >> 3) * C2P + (prD * 18 + pcD) * 16 + (col & 7) * 2] = f2bf(v);
        }
    }
    __syncthreads();   // B4: c2 ready, c1 dead (C3 may overwrite)

    // ---- conv3 -> c3 (16 M-tiles; K=144->160, 5 mfma) ----
    for (int t = wv; t < 16; t += 4) {
        int band = t >> 1, tc = (t & 1) * 8;
        int rA = band * 2 + (col >> 3), cA = tc + (col & 7);
        f32x4 acc = {0.f, 0.f, 0.f, 0.f};
        #pragma unroll
        for (int q = 0; q < 5; ++q) {
            int tp = 2 * q + (g >> 1); if (tp > 8) tp = 8;
            int dr = tp / 3, dc = tp % 3;
            int half = g & 1;
            s16x8 Af = *(const s16x8*)&S[C2 + half * C2P + ((rA + dr) * 18 + (cA + dc)) * 16];
            acc = MFMA16(Af, fw3[q], acc, 0, 0, 0);
        }
        if (col < 4) {
            int rD = band * 2 + (g >> 1), c0 = tc + ((4 * g) & 7);
            #pragma unroll
            for (int i = 0; i < 4; ++i)
                *(float*)&S[C3 + ((rD * 16 + c0 + i) * 4 + col) * 4] = acc[i] + bias3_v;
        }
    }
    __syncthreads();   // B5: c3 ready

    // ---- sigmoid + diffusion update (f32) ----
    {
        int r = tid >> 4, c = tid & 15;
        f32x4 cc = *(const f32x4*)&S[C3 + tid * 16];
        float cN = sigmoidf_(cc[0]), cS = sigmoidf_(cc[1]);
        float cE = sigmoidf_(cc[2]), cWd = sigmoidf_(cc[3]);
        float v  = s_x[(r + 4) * 24 + c + 4];
        float gN = s_x[(r + 3) * 24 + c + 4] - v;
        float gS = s_x[(r + 5) * 24 + c + 4] - v;
        float gE = s_x[(r + 4) * 24 + c + 5] - v;
        float gW = s_x[(r + 4) * 24 + c + 3] - v;
        xout[((size_t)bz * HH + (i0 + r)) * WW + (j0 + c)] =
            v + LAMV * (cN * gN + cS * gS + cE * gE + cWd * gW);
    }
}

extern "C" void kernel_launch(void* const* d_in, const int* in_sizes, int n_in,
                              void* d_out, int out_size, void* d_ws, size_t ws_size,
                              hipStream_t stream) {
    (void)in_sizes; (void)n_in; (void)out_size; (void)ws_size;
    const float* x   = (const float*)d_in[0];
    const float* gw1 = (const float*)d_in[1];
    const float* gb1 = (const float*)d_in[2];
    const float* bng = (const float*)d_in[3];
    const float* bnb = (const float*)d_in[4];
    const float* bnm = (const float*)d_in[5];
    const float* bnv = (const float*)d_in[6];
    const float* gw2 = (const float*)d_in[7];
    const float* gb2 = (const float*)d_in[8];
    const float* cw1 = (const float*)d_in[9];
    const float* cb1 = (const float*)d_in[10];
    const float* cw2 = (const float*)d_in[11];
    const float* cb2 = (const float*)d_in[12];
    const float* cw3 = (const float*)d_in[13];
    const float* cb3 = (const float*)d_in[14];
    float* out = (float*)d_out;

    char* base = (char*)d_ws;
    const size_t PX    = (size_t)NB * HH * WW;
    const size_t GU16B = PX * 8 * 2;   // 32 MiB guid bf16 pixel-major
    const size_t XB    = PX * 4;       //  8 MiB

    unsigned short* guid16 = (unsigned short*)base;
    float* bufA            = (float*)(base + GU16B);
    unsigned short* wpk    = (unsigned short*)(base + GU16B + XB);

    dim3 grid3(WW / TT, HH / TT, NB);
    prep_kernel<<<1, 256, 0, stream>>>(cw1, cw2, cw3, gw2, wpk);
    guidance_kernel<<<grid3, 256, 0, stream>>>(x, gw1, gb1, bng, bnb, bnm, bnv, gb2, wpk, guid16);

    const float* cur = x;
    for (int it = 0; it < 10; ++it) {
        float* dst = (it & 1) ? out : bufA;   // it9 (odd) lands in d_out
        iter_kernel<<<8192, BSI, 0, stream>>>(cur, dst, guid16, wpk, cb1, cb2, cb3);
        cur = dst;
    }
}

// Round 10
// 1450.928 us; speedup vs baseline: 264.9305x; 1.0410x over previous
//
#include <hip/hip_runtime.h>
#include <hip/hip_bf16.h>

#define HH 512
#define WW 512
#define NB 8
#define TT 16
#define BSI 256
#define EPSV 1e-5f
#define LAMV 0.1f

typedef __attribute__((ext_vector_type(4))) float f32x4;
typedef __attribute__((ext_vector_type(4))) short s16x4;
typedef __attribute__((ext_vector_type(8))) short s16x8;

#define MFMA16 __builtin_amdgcn_mfma_f32_16x16x32_bf16

// packed-weight blob offsets (bytes)
#define W2PK 0        // [9 tap][16 co][32 ch] bf16            (9216 B)
#define W3PK 9216     // [5 row][160 k] bf16                   (1600 B)
#define W1PKG 10816   // [32 co][64 k]  k=tap*4+gradch         (4096 B)
#define W1PKU 14912   // [32 co][96 k]  k=tap*8+guidch         (6144 B)
#define W4PK  21056   // [16 col][160 k] gw2, k=tap*16+ci      (5120 B)
#define WPKTOT 26176

__device__ __forceinline__ float sigmoidf_(float v) { return 1.0f / (1.0f + __expf(-v)); }

__device__ __forceinline__ short f2bf(float f) {
    __hip_bfloat16 h = __float2bfloat16(f);
    short s; __builtin_memcpy(&s, &h, 2); return s;
}
__device__ __forceinline__ unsigned pack2bf(float a, float b) {
    __hip_bfloat16 ha = __float2bfloat16(a), hb = __float2bfloat16(b);
    unsigned short ua, ub;
    __builtin_memcpy(&ua, &ha, 2); __builtin_memcpy(&ub, &hb, 2);
    return (unsigned)ua | ((unsigned)ub << 16);
}

// ---------------------------------------------------------------------------
// prep: pack conv weights into fragment-major bf16 blobs (runs once, 1 block)
// ---------------------------------------------------------------------------
__global__ __launch_bounds__(256) void prep_kernel(
    const float* __restrict__ cw1, const float* __restrict__ cw2,
    const float* __restrict__ cw3, const float* __restrict__ gw2,
    unsigned short* __restrict__ wpk)
{
    const int tid = threadIdx.x;
    for (int e = tid; e < 4608; e += 256) {
        int ch = e & 31, co = (e >> 5) & 15, t = e >> 9;
        wpk[W2PK / 2 + e] = (unsigned short)f2bf(cw2[(co * 32 + ch) * 9 + t]);
    }
    for (int e = tid; e < 800; e += 256) {
        int k = e % 160, row = e / 160;
        float v = 0.f;
        if (row < 4 && k < 144) { int tp = k / 16, ci = k & 15; v = cw3[(row * 16 + ci) * 9 + tp]; }
        wpk[W3PK / 2 + e] = (unsigned short)f2bf(v);
    }
    for (int e = tid; e < 2048; e += 256) {
        int k = e & 63, co = e >> 6;
        float v = 0.f;
        if (k < 36) { int tp = k >> 2, ch = k & 3; v = cw1[(co * 12 + ch) * 9 + tp]; }
        wpk[W1PKG / 2 + e] = (unsigned short)f2bf(v);
    }
    for (int e = tid; e < 3072; e += 256) {
        int k = e % 96, co = e / 96;
        float v = 0.f;
        if (k < 72) { int tp = k >> 3, ch = k & 7; v = cw1[(co * 12 + 4 + ch) * 9 + tp]; }
        wpk[W1PKU / 2 + e] = (unsigned short)f2bf(v);
    }
    for (int e = tid; e < 2560; e += 256) {
        int k = e % 160, col = e / 160;
        float v = 0.f;
        if (col < 8 && k < 144) { int tp = k / 16, ci = k & 15; v = gw2[(col * 16 + ci) * 9 + tp]; }
        wpk[W4PK / 2 + e] = (unsigned short)f2bf(v);
    }
}

// ---------------------------------------------------------------------------
// Guidance (runs once): avgpool3 -> dilated conv(1->16)+BN+relu (VALU) ->
// conv(16->8, MFMA K=160)+sigmoid. Output bf16 pixel-major [b][i][j][8].
// ---------------------------------------------------------------------------
__global__ __launch_bounds__(256) void guidance_kernel(
    const float* __restrict__ x, const float* __restrict__ gw1, const float* __restrict__ gb1,
    const float* __restrict__ bng, const float* __restrict__ bnb, const float* __restrict__ bnm,
    const float* __restrict__ bnv, const float* __restrict__ gb2,
    const unsigned short* __restrict__ wpk, unsigned short* __restrict__ guid16)
{
    constexpr int WG1 = 0, BNO = 576, SX = 768, SXS = 3904, SG = 6608, SR = 768;
    constexpr int GP = 18 * 18 * 16;   // 5184
    __shared__ __align__(16) char S[16976];

    const int tid = threadIdx.x;
    const int b  = blockIdx.z;
    const int i0 = blockIdx.y * TT, j0 = blockIdx.x * TT;
    const float* xb = x + (size_t)b * HH * WW;

    const int lane = tid & 63;
    const int g = lane >> 4;
    const int col = lane & 15;
    const int wv = tid >> 6;

    for (int e = tid; e < 144; e += 256) {
        int co = e % 16, t = e / 16;
        ((float*)&S[WG1])[t * 16 + co] = gw1[co * 9 + t];
    }
    if (tid < 16) {
        float iv = bng[tid] * rsqrtf(bnv[tid] + EPSV);
        ((float*)&S[BNO])[tid]      = iv;
        ((float*)&S[BNO + 64])[tid] = bnb[tid] - bnm[tid] * iv;
        ((float*)&S[BNO + 128])[tid] = gb1[tid];
    }
    s16x8 fw4[5];
    #pragma unroll
    for (int q = 0; q < 5; ++q)
        fw4[q] = *(const s16x8*)&wpk[W4PK / 2 + col * 160 + q * 32 + g * 8];
    const float b2v = (col < 8) ? gb2[col] : 0.f;

    for (int e = tid; e < 784; e += 256) {
        int u = e / 28, v = e % 28;
        int gi = i0 - 6 + u, gj = j0 - 6 + v;
        float val = 0.f;
        if ((unsigned)gi < (unsigned)HH && (unsigned)gj < (unsigned)WW) val = xb[gi * WW + gj];
        ((float*)&S[SX])[e] = val;
    }
    __syncthreads();   // B1

    for (int e = tid; e < 676; e += 256) {
        int u = e / 26, v = e % 26;
        int gi = i0 - 5 + u, gj = j0 - 5 + v;
        float val = 0.f;
        if ((unsigned)gi < (unsigned)HH && (unsigned)gj < (unsigned)WW) {
            float s = 0.f;
            #pragma unroll
            for (int du = 0; du < 3; ++du)
                #pragma unroll
                for (int dv = 0; dv < 3; ++dv)
                    s += ((float*)&S[SX])[(u + du) * 28 + (v + dv)];
            val = s * (1.0f / 9.0f);
        }
        ((float*)&S[SXS])[e] = val;
    }
    __syncthreads();   // B2

    for (int e = tid; e < 324; e += 256) {
        int r = e / 18, c = e % 18;
        int gi = i0 - 1 + r, gj = j0 - 1 + c;
        bool in = (unsigned)gi < (unsigned)HH && (unsigned)gj < (unsigned)WW;
        float acc[16];
        #pragma unroll
        for (int k = 0; k < 16; ++k) acc[k] = ((float*)&S[BNO + 128])[k];
        #pragma unroll
        for (int kh = 0; kh < 3; ++kh)
            #pragma unroll
            for (int kw = 0; kw < 3; ++kw) {
                float av = ((float*)&S[SXS])[(r + 2 * kh + 2) * 26 + (c + 2 * kw + 2)];
                #pragma unroll
                for (int q4 = 0; q4 < 4; ++q4) {
                    const float4 w = *(const float4*)&((float*)&S[WG1])[(kh * 3 + kw) * 16 + q4 * 4];
                    acc[q4*4+0] = fmaf(w.x, av, acc[q4*4+0]);
                    acc[q4*4+1] = fmaf(w.y, av, acc[q4*4+1]);
                    acc[q4*4+2] = fmaf(w.z, av, acc[q4*4+2]);
                    acc[q4*4+3] = fmaf(w.w, av, acc[q4*4+3]);
                }
            }
        float gval[16];
        #pragma unroll
        for (int k = 0; k < 16; ++k) {
            float v = acc[k] * ((float*)&S[BNO])[k] + ((float*)&S[BNO + 64])[k];
            gval[k] = in ? fmaxf(v, 0.f) : 0.f;
        }
        uint4 h0, h1;
        h0.x = pack2bf(gval[0], gval[1]);  h0.y = pack2bf(gval[2], gval[3]);
        h0.z = pack2bf(gval[4], gval[5]);  h0.w = pack2bf(gval[6], gval[7]);
        h1.x = pack2bf(gval[8], gval[9]);  h1.y = pack2bf(gval[10], gval[11]);
        h1.z = pack2bf(gval[12], gval[13]); h1.w = pack2bf(gval[14], gval[15]);
        *(uint4*)&S[SG + (r * 18 + c) * 16]      = h0;
        *(uint4*)&S[SG + GP + (r * 18 + c) * 16] = h1;
    }
    __syncthreads();   // B3

    for (int t = wv; t < 16; t += 4) {
        int band = t >> 1, tc = (t & 1) * 8;
        int rA = band * 2 + (col >> 3), cA = tc + (col & 7);
        f32x4 acc = {0.f, 0.f, 0.f, 0.f};
        #pragma unroll
        for (int q = 0; q < 5; ++q) {
            int tp = 2 * q + (g >> 1); if (tp > 8) tp = 8;
            int dr = tp / 3, dc = tp % 3;
            s16x8 Af = *(const s16x8*)&S[SG + (g & 1) * GP + ((rA + dr) * 18 + (cA + dc)) * 16];
            acc = MFMA16(Af, fw4[q], acc, 0, 0, 0);
        }
        if (col < 8) {
            int rD = band * 2 + (g >> 1), c0 = tc + ((4 * g) & 7);
            #pragma unroll
            for (int i = 0; i < 4; ++i) {
                float s = sigmoidf_(acc[i] + b2v);
                *(short*)&S[SR + ((rD * 16 + c0 + i) * 8 + col) * 2] = f2bf(s);
            }
        }
    }
    __syncthreads();   // B4

    {
        uint4 u = *(const uint4*)&S[SR + tid * 16];
        int gi = i0 + (tid >> 4), gj = j0 + (tid & 15);
        *(uint4*)&guid16[(((size_t)b * HH + gi) * WW + gj) * 8] = u;
    }
}

// ---------------------------------------------------------------------------
// Fused diffusion iteration, MFMA bf16 16x16x32, no Z intermediate.
// Block-uniform EDGE specialization: interior blocks (88%) skip all bounds
// checks/clamps and use float4 x staging. Edge blocks keep masked path.
// LDS: s_x 2304 | ACTG [22][22][4] 3872 | ACTU [22][22][8] 7744 |
//      C1 4x[20][20][8] 25600 | C2 2x[18][18][8] 10368 | C3 alias C1.
// TOT 49888 -> 3 blocks/CU. XCD swizzle: one batch-image per XCD.
// ---------------------------------------------------------------------------
__global__ __launch_bounds__(BSI) void iter_kernel(
    const float* __restrict__ xin, float* __restrict__ xout,
    const unsigned short* __restrict__ guid16,
    const unsigned short* __restrict__ wpk, const float* __restrict__ cb1,
    const float* __restrict__ cb2, const float* __restrict__ cb3)
{
    constexpr int ACTG = 2304;
    constexpr int ACTU = 6176;
    constexpr int C1   = 13920;
    constexpr int C2   = 39520;
    constexpr int C3   = C1;           // aliases dead C1 after B4
    constexpr int TOT  = 49888;
    constexpr int C1P  = 6400;         // c1 plane stride (20*20*8*2)
    constexpr int C2P  = 5184;         // c2 plane stride (18*18*8*2)

    __shared__ __align__(16) char S[TOT];
    float* s_x = (float*)S;

    const int tid = threadIdx.x;
    // XCD-aware swizzle: 8192 blocks, image bz -> XCD bz
    const int flat = blockIdx.x;
    const int nid  = (flat & 7) * 1024 + (flat >> 3);
    const int bz   = nid >> 10;
    const int i0   = ((nid >> 5) & 31) * TT;
    const int j0   = (nid & 31) * TT;
    const int o = i0 - 4, p = j0 - 4;
    const float* xb = xin + (size_t)bz * HH * WW;
    const unsigned short* gub = guid16 + (size_t)bz * HH * WW * 8;
    // block-uniform: all halo accesses in-image?
    const bool edge = (i0 == 0) || (i0 == HH - TT) || (j0 == 0) || (j0 == WW - TT);

    // ---- phase 0: stage x tile + guid (guid independent of s_x) ----
    if (!edge) {
        for (int e = tid; e < 144; e += BSI) {
            int r = e / 6, c4 = (e % 6) * 4;
            *(float4*)&s_x[r * 24 + c4] = *(const float4*)&xb[(size_t)(o + r) * WW + (p + c4)];
        }
        for (int e = tid; e < 484; e += BSI) {
            int r = e / 22, c = e % 22;
            *(uint4*)&S[ACTU + (r * 22 + c) * 16] =
                *(const uint4*)&gub[((size_t)(o + 1 + r) * WW + (p + 1 + c)) * 8];
        }
    } else {
        for (int e = tid; e < 576; e += BSI) {
            int r = e / 24, c = e % 24;
            int gi = min(max(o + r, 0), HH - 1);
            int gj = min(max(p + c, 0), WW - 1);
            s_x[e] = xb[gi * WW + gj];
        }
        for (int e = tid; e < 484; e += BSI) {
            int r = e / 22, c = e % 22;
            int gi = o + 1 + r, gj = p + 1 + c;
            bool in = ((unsigned)gi < (unsigned)HH) && ((unsigned)gj < (unsigned)WW);
            uint4 gu = make_uint4(0u, 0u, 0u, 0u);
            if (in) gu = *(const uint4*)&gub[((size_t)gi * WW + gj) * 8];
            *(uint4*)&S[ACTU + (r * 22 + c) * 16] = gu;
        }
    }

    const int lane = tid & 63;
    const int g = lane >> 4;
    const int col = lane & 15;
    const int wv = tid >> 6;

    const float bias2_v = cb2[col];
    const float bias3_v = (col < 4) ? cb3[col] : 0.f;
    const float b1v0 = cb1[col];
    const float b1v1 = cb1[col + 16];

    // B-fragments from packed global blob (L1/L2-hot, coalesced)
    s16x8 fw2[9], fw3[5], fwg[4], fwu[6];
    #pragma unroll
    for (int t = 0; t < 9; ++t)
        fw2[t] = *(const s16x8*)&wpk[W2PK / 2 + (t * 16 + col) * 32 + g * 8];
    {
        int w3r = col < 4 ? col : 4;
        #pragma unroll
        for (int q = 0; q < 5; ++q)
            fw3[q] = *(const s16x8*)&wpk[W3PK / 2 + w3r * 160 + q * 32 + g * 8];
    }
    #pragma unroll
    for (int h = 0; h < 2; ++h) {
        #pragma unroll
        for (int mf = 0; mf < 2; ++mf)
            fwg[h * 2 + mf] = *(const s16x8*)&wpk[W1PKG / 2 + (col + 16 * h) * 64 + mf * 32 + g * 8];
        #pragma unroll
        for (int q = 0; q < 3; ++q)
            fwu[h * 3 + q] = *(const s16x8*)&wpk[W1PKU / 2 + (col + 16 * h) * 96 + q * 32 + g * 8];
    }
    __syncthreads();   // B1: s_x + ACTU staged

    // ---- gradients (edge-clamped diffs; 0 off-image), rel [1,23) ----
    if (!edge) {
        for (int e = tid; e < 484; e += BSI) {
            int r = e / 22, c = e % 22;
            float v  = s_x[(r + 1) * 24 + c + 1];
            float gN = s_x[(r + 0) * 24 + c + 1] - v;
            float gS = s_x[(r + 2) * 24 + c + 1] - v;
            float gE = s_x[(r + 1) * 24 + c + 2] - v;
            float gW = s_x[(r + 1) * 24 + c + 0] - v;
            *(uint2*)&S[ACTG + (r * 22 + c) * 8] = make_uint2(pack2bf(gN, gS), pack2bf(gE, gW));
        }
    } else {
        for (int e = tid; e < 484; e += BSI) {
            int r = e / 22, c = e % 22;
            int gi = o + 1 + r, gj = p + 1 + c;
            bool in = ((unsigned)gi < (unsigned)HH) && ((unsigned)gj < (unsigned)WW);
            float v  = s_x[(r + 1) * 24 + c + 1];
            float gN = s_x[(r + 0) * 24 + c + 1] - v;
            float gS = s_x[(r + 2) * 24 + c + 1] - v;
            float gE = s_x[(r + 1) * 24 + c + 2] - v;
            float gW = s_x[(r + 1) * 24 + c + 0] - v;
            if (!in) { gN = gS = gE = gW = 0.f; }
            *(uint2*)&S[ACTG + (r * 22 + c) * 8] = make_uint2(pack2bf(gN, gS), pack2bf(gE, gW));
        }
    }
    __syncthreads();   // B2: activations ready

    // ---- conv1 -> c1 planes (30 M-tiles: 10 bands x cols {0,8,12}) ----
    {
        const int t0 = 2 * g, t1 = t0 + 1;
        const int dr0 = t0 / 3, dc0 = t0 % 3, dr1 = t1 / 3, dc1 = t1 % 3;
        for (int t = wv; t < 30; t += 4) {
            int band = t / 3, m3 = t % 3;
            int tc = m3 * 8 - (m3 >> 1) * 4;          // {0,8,12}
            int prA = band * 2 + (col >> 3), pcA = tc + (col & 7);
            s16x4 a0 = *(const s16x4*)&S[ACTG + ((prA + dr0) * 22 + (pcA + dc0)) * 8];
            s16x4 a1 = *(const s16x4*)&S[ACTG + ((prA + dr1) * 22 + (pcA + dc1)) * 8];
            s16x4 a2 = *(const s16x4*)&S[ACTG + ((prA + 2) * 22 + (pcA + 2)) * 8];   // tap8
            s16x8 A1 = __builtin_shufflevector(a0, a1, 0, 1, 2, 3, 4, 5, 6, 7);
            s16x8 A2 = __builtin_shufflevector(a2, a2, 0, 1, 2, 3, 0, 1, 2, 3);
            s16x8 Au[3];
            #pragma unroll
            for (int q = 0; q < 3; ++q) {
                int tg = q * 4 + g;
                int dtr = tg / 3, dtc = tg % 3;
                if (tg <= 8)
                    Au[q] = *(const s16x8*)&S[ACTU + ((prA + dtr) * 22 + (pcA + dtc)) * 16];
                else
                    Au[q] = (s16x8){0, 0, 0, 0, 0, 0, 0, 0};
            }
            int prD = band * 2 + (g >> 1);
            int pc0 = tc + ((4 * g) & 7);
            #pragma unroll
            for (int h = 0; h < 2; ++h) {
                int co = col + 16 * h;
                float bi = h ? b1v1 : b1v0;
                f32x4 acc = {bi, bi, bi, bi};
                acc = MFMA16(A1, fwg[h * 2 + 0], acc, 0, 0, 0);
                acc = MFMA16(A2, fwg[h * 2 + 1], acc, 0, 0, 0);
                acc = MFMA16(Au[0], fwu[h * 3 + 0], acc, 0, 0, 0);
                acc = MFMA16(Au[1], fwu[h * 3 + 1], acc, 0, 0, 0);
                acc = MFMA16(Au[2], fwu[h * 3 + 2], acc, 0, 0, 0);
                char* dst = &S[C1 + (co >> 3) * C1P + (prD * 20 + pc0) * 16 + (co & 7) * 2];
                if (!edge) {
                    #pragma unroll
                    for (int i = 0; i < 4; ++i)
                        *(short*)(dst + i * 16) = f2bf(fmaxf(acc[i], 0.f));
                } else {
                    bool rin = (unsigned)(o + 2 + prD) < (unsigned)HH;
                    #pragma unroll
                    for (int i = 0; i < 4; ++i) {
                        bool in = rin && ((unsigned)(p + 2 + pc0 + i) < (unsigned)WW);
                        *(short*)(dst + i * 16) = f2bf(in ? fmaxf(acc[i], 0.f) : 0.f);
                    }
                }
            }
        }
    }
    __syncthreads();   // B3: c1 ready

    // ---- conv2 -> c2 planes (27 M-tiles: 9 bands x cols {0,8,10}) ----
    for (int t = wv; t < 27; t += 4) {
        int band = t / 3, m3 = t % 3;
        int tc = m3 * 8 - (m3 >> 1) * 6;              // {0,8,10}
        int prA = band * 2 + (col >> 3), pcA = tc + (col & 7);
        f32x4 acc = {0.f, 0.f, 0.f, 0.f};
        #pragma unroll
        for (int tp = 0; tp < 9; ++tp) {
            int dr = tp / 3, dc = tp % 3;
            s16x8 Af = *(const s16x8*)&S[C1 + g * C1P + ((prA + dr) * 20 + (pcA + dc)) * 16];
            acc = MFMA16(Af, fw2[tp], acc, 0, 0, 0);
        }
        int prD = band * 2 + (g >> 1);
        int pc0 = tc + ((4 * g) & 7);
        char* dst = &S[C2 + (col >> 3) * C2P + (prD * 18 + pc0) * 16 + (col & 7) * 2];
        if (!edge) {
            #pragma unroll
            for (int i = 0; i < 4; ++i)
                *(short*)(dst + i * 16) = f2bf(fmaxf(acc[i] + bias2_v, 0.f));
        } else {
            bool rin = (unsigned)(o + 3 + prD) < (unsigned)HH;
            #pragma unroll
            for (int i = 0; i < 4; ++i) {
                bool in = rin && ((unsigned)(p + 3 + pc0 + i) < (unsigned)WW);
                *(short*)(dst + i * 16) = f2bf(in ? fmaxf(acc[i] + bias2_v, 0.f) : 0.f);
            }
        }
    }
    __syncthreads();   // B4: c2 ready, c1 dead (C3 may overwrite)

    // ---- conv3 -> c3 (16 M-tiles; K=144->160, 5 mfma) ----
    for (int t = wv; t < 16; t += 4) {
        int band = t >> 1, tc = (t & 1) * 8;
        int rA = band * 2 + (col >> 3), cA = tc + (col & 7);
        f32x4 acc = {0.f, 0.f, 0.f, 0.f};
        #pragma unroll
        for (int q = 0; q < 5; ++q) {
            int tp = 2 * q + (g >> 1); if (tp > 8) tp = 8;
            int dr = tp / 3, dc = tp % 3;
            int half = g & 1;
            s16x8 Af = *(const s16x8*)&S[C2 + half * C2P + ((rA + dr) * 18 + (cA + dc)) * 16];
            acc = MFMA16(Af, fw3[q], acc, 0, 0, 0);
        }
        if (col < 4) {
            int rD = band * 2 + (g >> 1), c0 = tc + ((4 * g) & 7);
            #pragma unroll
            for (int i = 0; i < 4; ++i)
                *(float*)&S[C3 + ((rD * 16 + c0 + i) * 4 + col) * 4] = acc[i] + bias3_v;
        }
    }
    __syncthreads();   // B5: c3 ready

    // ---- sigmoid + diffusion update (f32) ----
    {
        int r = tid >> 4, c = tid & 15;
        f32x4 cc = *(const f32x4*)&S[C3 + tid * 16];
        float cN = sigmoidf_(cc[0]), cS = sigmoidf_(cc[1]);
        float cE = sigmoidf_(cc[2]), cWd = sigmoidf_(cc[3]);
        float v  = s_x[(r + 4) * 24 + c + 4];
        float gN = s_x[(r + 3) * 24 + c + 4] - v;
        float gS = s_x[(r + 5) * 24 + c + 4] - v;
        float gE = s_x[(r + 4) * 24 + c + 5] - v;
        float gW = s_x[(r + 4) * 24 + c + 3] - v;
        xout[((size_t)bz * HH + (i0 + r)) * WW + (j0 + c)] =
            v + LAMV * (cN * gN + cS * gS + cE * gE + cWd * gW);
    }
}

extern "C" void kernel_launch(void* const* d_in, const int* in_sizes, int n_in,
                              void* d_out, int out_size, void* d_ws, size_t ws_size,
                              hipStream_t stream) {
    (void)in_sizes; (void)n_in; (void)out_size; (void)ws_size;
    const float* x   = (const float*)d_in[0];
    const float* gw1 = (const float*)d_in[1];
    const float* gb1 = (const float*)d_in[2];
    const float* bng = (const float*)d_in[3];
    const float* bnb = (const float*)d_in[4];
    const float* bnm = (const float*)d_in[5];
    const float* bnv = (const float*)d_in[6];
    const float* gw2 = (const float*)d_in[7];
    const float* gb2 = (const float*)d_in[8];
    const float* cw1 = (const float*)d_in[9];
    const float* cb1 = (const float*)d_in[10];
    const float* cw2 = (const float*)d_in[11];
    const float* cb2 = (const float*)d_in[12];
    const float* cw3 = (const float*)d_in[13];
    const float* cb3 = (const float*)d_in[14];
    float* out = (float*)d_out;

    char* base = (char*)d_ws;
    const size_t PX    = (size_t)NB * HH * WW;
    const size_t GU16B = PX * 8 * 2;   // 32 MiB guid bf16 pixel-major
    const size_t XB    = PX * 4;       //  8 MiB

    unsigned short* guid16 = (unsigned short*)base;
    float* bufA            = (float*)(base + GU16B);
    unsigned short* wpk    = (unsigned short*)(base + GU16B + XB);

    dim3 grid3(WW / TT, HH / TT, NB);
    prep_kernel<<<1, 256, 0, stream>>>(cw1, cw2, cw3, gw2, wpk);
    guidance_kernel<<<grid3, 256, 0, stream>>>(x, gw1, gb1, bng, bnb, bnm, bnv, gb2, wpk, guid16);

    const float* cur = x;
    for (int it = 0; it < 10; ++it) {
        float* dst = (it & 1) ? out : bufA;   // it9 (odd) lands in d_out
        iter_kernel<<<8192, BSI, 0, stream>>>(cur, dst, guid16, wpk, cb1, cb2, cb3);
        cur = dst;
    }
}